// Round 18
// baseline (403.329 us; speedup 1.0000x reference)
//
#include <hip/hip_runtime.h>
#include <hip/hip_bf16.h>

typedef __hip_bfloat16 bf16;
typedef __attribute__((ext_vector_type(8))) short  s16x8;  // 8 bf16 = 4 VGPR (MFMA A/B frag)
typedef __attribute__((ext_vector_type(4))) float  f32x4;  // MFMA C/D frag

static constexpr int S    = 2048;
static constexpr int D    = 4096;
static constexpr int H    = 32;
static constexpr int QL   = 1536;
static constexpr int KVL  = 512;
static constexpr int NOPE = 128;
static constexpr int ROPE = 64;
static constexpr int QKH  = 192;
static constexpr int VH   = 128;
static constexpr int CAT  = 576;
static constexpr int CAT2 = 192;    // absorbed head dim: 128 nope + 64 rope
static constexpr int NCAT = 2112;   // QL + CAT (merged q_a/kv_a GEMM width)
static constexpr float EPS = 1e-6f;

__device__ __forceinline__ void stf(float* p, float v){ *p = v; }
__device__ __forceinline__ void stf(bf16* p, float v){ *p = __float2bfloat16(v); }

__device__ __forceinline__ float wave_sum(float v){
#pragma unroll
  for (int off = 32; off; off >>= 1) v += __shfl_xor(v, off, 64);
  return v;
}

__device__ __forceinline__ void gload16(const bf16* src, unsigned short* dst){
  __builtin_amdgcn_global_load_lds(
      (const __attribute__((address_space(1))) unsigned int*)src,
      (__attribute__((address_space(3))) unsigned int*)dst, 16, 0, 0);
}

// grid-strided f32->bf16 cast segment (256-thread blocks)
__device__ __forceinline__ void cast_seg(const float* __restrict__ in,
                                         bf16* __restrict__ out, long long n4,
                                         int brel, int nblk)
{
  long long i = (long long)brel * 256 + threadIdx.x;
  const long long stride = (long long)nblk * 256;
  for (; i < n4; i += stride) {
    float4 v = ((const float4*)in)[i];
    union { bf16 b[4]; uint2 u; } t;
    t.b[0] = __float2bfloat16(v.x); t.b[1] = __float2bfloat16(v.y);
    t.b[2] = __float2bfloat16(v.z); t.b[3] = __float2bfloat16(v.w);
    *(uint2*)(out + i * 4) = t.u;
  }
}

// ---------------------------------------------------------------------------
// standalone f32->bf16 cast (full-machine BW; used for w_o)
// ---------------------------------------------------------------------------
__global__ __launch_bounds__(256)
void cast_kernel(const float* __restrict__ in, bf16* __restrict__ out, long long n4)
{
  cast_seg(in, out, n4, blockIdx.x, gridDim.x);
}

// ---------------------------------------------------------------------------
// cast_all (verified R16/R17): ALL pre-GEMM casts in one dispatch.
// ---------------------------------------------------------------------------
__global__ __launch_bounds__(256)
void cast_all(const float* __restrict__ h2, bf16* __restrict__ hb,
              const float* __restrict__ w_q_a, const float* __restrict__ w_kv_a,
              bf16* __restrict__ wcat_b,
              const float* __restrict__ w_uk, bf16* __restrict__ wukb,
              const float* __restrict__ w_uv, bf16* __restrict__ wuv_t)
{
  const int b = blockIdx.x;
  if (b < 512) {
    cast_seg(h2, hb, (long long)S * D / 4, b, 512);
  } else if (b < 896) {
    cast_seg(w_q_a, wcat_b, (long long)QL * D / 4, b - 512, 384);
  } else if (b < 1040) {
    cast_seg(w_kv_a, wcat_b + (long long)QL * D, (long long)CAT * D / 4, b - 896, 144);
  } else if (b < 1168) {
    cast_seg(w_uk, wukb, (long long)H * NOPE * KVL / 4, b - 1040, 128);
  } else {
    // wuv tcast: in f32 [H][KVL][VH] -> out bf16 [H][VH][KVL], 32x32 tiles
    const int t2 = b - 1168;                 // 0..2047 = (VH/32) x (KVL/32) x H
    const int bx = t2 & 3, by = (t2 >> 2) & 15, bz = t2 >> 6;
    const float* in = w_uv + (long long)bz * KVL * VH;
    bf16* out = wuv_t + (long long)bz * KVL * VH;
    const int c0 = bx * 32, r0 = by * 32;
    __shared__ float t[32][33];
    const int tx = threadIdx.x & 31, ty = threadIdx.x >> 5;
#pragma unroll
    for (int p = 0; p < 4; p++)
      t[ty + p * 8][tx] = in[(long long)(r0 + ty + p * 8) * VH + c0 + tx];
    __syncthreads();
#pragma unroll
    for (int p = 0; p < 4; p++)
      out[(long long)(c0 + ty + p * 8) * KVL + r0 + tx] = __float2bfloat16(t[tx][ty + p * 8]);
  }
}

// ---------------------------------------------------------------------------
// f32 add: dst += src (K-split combine for the out GEMM)
// ---------------------------------------------------------------------------
__global__ __launch_bounds__(256)
void add_kernel(float* __restrict__ dst, const float* __restrict__ src, long long n4)
{
  long long i = (long long)blockIdx.x * 256 + threadIdx.x;
  const long long stride = (long long)gridDim.x * 256;
  for (; i < n4; i += stride) {
    float4 a = ((const float4*)dst)[i];
    const float4 b = ((const float4*)src)[i];
    a.x += b.x; a.y += b.y; a.z += b.z; a.w += b.w;
    ((float4*)dst)[i] = a;
  }
}

// ---------------------------------------------------------------------------
// mgemm3 CORE v2 (phase-lite): 256x256 tile, BK=64, 8 waves, counted-vmcnt.
// R17 base (verified) + fine stage interleave: the 8-load stage burst is
// split into half-tiles -- A[0:128)+B[0:128) issued before the buf-ready
// barrier (vmcnt(4): oldest-first semantics waits exactly the previous
// tile's 8 loads, leaves these 4 in flight), A[128:256)+B[128:256) issued
// BETWEEN MFMA groups so VMEM issue doesn't stall the MFMA stream (m196:
// the fine interleave is the lever).  Barrier skeleton unchanged (2/K-tile).
// B-frags read once per tile; A in 4 groups of 4; MFMA in 4 setprio groups.
// EPI=0 plain / EPI=1 ABSORB / EPI=2 q2-ROPE (epilogues verified, unchanged).
// ---------------------------------------------------------------------------
template<typename TC, int EPI>
__device__ __forceinline__ void mg3_core(
    unsigned short (*As)[256 * 64], unsigned short (*Bs)[256 * 64],
    const bf16* __restrict__ A, const bf16* __restrict__ B,
    TC* __restrict__ C, TC* __restrict__ C2,
    const float* __restrict__ cosp, const float* __restrict__ sinp,
    int N, int K, int lda, int ldb, int ldc, int bx, int by)
{
  const int tid = threadIdx.x;
  const int w = tid >> 6;
  const int lane = tid & 63;
  const int l15 = lane & 15, g = lane >> 4;
  const int wr = w >> 2, wc = w & 3;
  const int m0 = by * 256, n0 = bx * 256;

  const bf16* asrc[4];
  const bf16* bsrc[4];
#pragma unroll
  for (int j = 0; j < 4; j++) {
    const int f = j * 512 + tid;
    const int row = f >> 3;                 // 0..255 (j chunk = 64 rows)
    const int cg = ((f & 7) ^ (row & 7)) * 8;
    asrc[j] = A + (long long)(m0 + row) * lda + cg;
    int br = n0 + row; if (br >= N) br = N - 1;
    bsrc[j] = B + (long long)br * ldb + cg;
  }

  // full-tile stage (prologue only)
  auto stage = [&](int b, int k0) {
#pragma unroll
    for (int j = 0; j < 4; j++) {
      gload16(asrc[j] + k0, &As[b][(j * 512 + w * 64) * 8]);
      gload16(bsrc[j] + k0, &Bs[b][(j * 512 + w * 64) * 8]);
    }
  };
  // half-tile stages: h=0 A rows 0-127 (j=0,1); h=1 A rows 128-255;
  //                   h=2 B rows 0-127;        h=3 B rows 128-255
  auto stage_h = [&](int b, int k0, int h) {
    const int j0 = (h & 1) * 2;
#pragma unroll
    for (int j = 0; j < 2; j++) {
      if (h < 2) gload16(asrc[j0 + j] + k0, &As[b][((j0 + j) * 512 + w * 64) * 8]);
      else       gload16(bsrc[j0 + j] + k0, &Bs[b][((j0 + j) * 512 + w * 64) * 8]);
    }
  };

  f32x4 acc[8][4];
#pragma unroll
  for (int i = 0; i < 8; i++)
#pragma unroll
    for (int j = 0; j < 4; j++) acc[i][j] = (f32x4){0.f, 0.f, 0.f, 0.f};

  const int ntk = K >> 6;
  stage(0, 0);                              // prologue: tile 0 (8 loads)

  for (int t = 0; t < ntk; ++t) {
    const int b = t & 1;
    const bool more = (t + 1 < ntk);
    const int nk0 = (t + 1) << 6;
    asm volatile("" ::: "memory");
    __builtin_amdgcn_s_barrier();           // all waves done reading buf b^1
    if (more) {
      stage_h(b ^ 1, nk0, 0);               // A[0:128) of t+1   (2 loads)
      stage_h(b ^ 1, nk0, 2);               // B[0:128) of t+1   (2 loads)
      asm volatile("s_waitcnt vmcnt(4)" ::: "memory");  // tile t's 8 landed
    } else {
      asm volatile("s_waitcnt vmcnt(0)" ::: "memory");
    }
    __builtin_amdgcn_s_barrier();           // tile t visible to all waves
    asm volatile("" ::: "memory");

    const unsigned short* Ab = &As[b][(wr * 128 + l15) * 64];
    const unsigned short* Bb = &Bs[b][(wc * 64 + l15) * 64];
    const int swz = l15 & 7;

    s16x8 bb[2][4];                         // B frags read once per tile
#pragma unroll
    for (int kk = 0; kk < 2; ++kk) {
      const int co = (((kk * 4 + g) ^ swz) * 8);
#pragma unroll
      for (int nt = 0; nt < 4; nt++)
        bb[kk][nt] = *(const s16x8*)(Bb + nt * 1024 + co);
    }
#pragma unroll
    for (int gph = 0; gph < 4; gph++) {     // 4 MFMA groups of 16
      if (more && gph == 1) stage_h(b ^ 1, nk0, 1);   // A[128:256) of t+1
      if (more && gph == 2) stage_h(b ^ 1, nk0, 3);   // B[128:256) of t+1
      s16x8 a[2][2];
#pragma unroll
      for (int kk = 0; kk < 2; kk++) {
        const int co = (((kk * 4 + g) ^ swz) * 8);
#pragma unroll
        for (int mi = 0; mi < 2; mi++)
          a[kk][mi] = *(const s16x8*)(Ab + (gph * 2 + mi) * 1024 + co);
      }
      __builtin_amdgcn_s_setprio(1);
#pragma unroll
      for (int kk = 0; kk < 2; kk++)
#pragma unroll
        for (int mi = 0; mi < 2; mi++)
#pragma unroll
          for (int nt = 0; nt < 4; nt++)
            acc[gph * 2 + mi][nt] = __builtin_amdgcn_mfma_f32_16x16x32_bf16(
                a[kk][mi], bb[kk][nt], acc[gph * 2 + mi][nt], 0, 0, 0);
      __builtin_amdgcn_s_setprio(0);
    }
  }

  if constexpr (EPI == 2) {
    const int blk = bx * 4 + wc;
    const int hh = blk / 3;
    const int dbase = (blk % 3) * 64;
    const bool isrope = (dbase == 128);
#pragma unroll
    for (int mt = 0; mt < 8; mt++) {
      const int row0 = m0 + wr * 128 + mt * 16 + g * 4;
#pragma unroll
      for (int nt = 0; nt < 4; nt++) {
        if (!isrope) {
          const int d = dbase + nt * 16 + l15;
#pragma unroll
          for (int r = 0; r < 4; r++)
            stf((bf16*)C + ((long long)hh * S + row0 + r) * CAT2 + d, acc[mt][nt][r]);
        } else {
          const int rr = nt * 16 + l15;     // rope dim 0..63
#pragma unroll
          for (int r = 0; r < 4; r++) {
            const int srow = row0 + r;
            const float x   = acc[mt][nt][r];
            const float xp  = acc[mt][nt ^ 2][r];     // col +/- 32, in-register
            const float rot = (rr < 32) ? -xp : xp;
            stf((bf16*)C + ((long long)hh * S + srow) * CAT2 + NOPE + rr,
                x * cosp[srow * ROPE + rr] + rot * sinp[srow * ROPE + rr]);
          }
        }
      }
    }
  } else {
#pragma unroll
    for (int mt = 0; mt < 8; mt++)
#pragma unroll
      for (int nt = 0; nt < 4; nt++) {
        const int col = n0 + wc * 64 + nt * 16 + l15;
        const int row0 = m0 + wr * 128 + mt * 16 + g * 4;
        if constexpr (EPI == 0) {
          if (col < N) {
#pragma unroll
            for (int r = 0; r < 4; r++)
              stf(C + (long long)(row0 + r) * ldc + col, acc[mt][nt][r]);
          }
        } else {
          if (col < H * NOPE) {               // key-absorb -> k2[h][row][n]
            TC* dst = C + ((long long)(col >> 7) * S + row0) * CAT2 + (col & 127);
#pragma unroll
            for (int r = 0; r < 4; r++)
              stf(dst + (long long)r * CAT2, acc[mt][nt][r]);
          } else {                             // value-absorb -> kv_vT[c'][row]
            TC* dst = C2 + (long long)(col - H * NOPE) * S + row0;
#pragma unroll
            for (int r = 0; r < 4; r++)
              stf(dst + r, acc[mt][nt][r]);
          }
        }
      }
  }
}

// ---------------------------------------------------------------------------
// standalone mgemm3 (qkv, out GEMMs): z-batch/K-split plumbing + core
// ---------------------------------------------------------------------------
template<typename TC, int EPI = 0>
__global__ __launch_bounds__(512, 2)
void mgemm3(const bf16* __restrict__ A, const bf16* __restrict__ B, TC* __restrict__ C,
            TC* __restrict__ C2, const float* __restrict__ cosp,
            const float* __restrict__ sinp,
            int M, int N, int K, int lda, int ldb, int ldc,
            long long sA, long long sB, long long sC)
{
  A += (long long)blockIdx.z * sA;
  B += (long long)blockIdx.z * sB;
  C += (long long)blockIdx.z * sC;
  __shared__ unsigned short As[2][256 * 64];   // 2 x 32 KB
  __shared__ unsigned short Bs[2][256 * 64];   // 2 x 32 KB
  mg3_core<TC, EPI>(As, Bs, A, B, C, C2, cosp, sinp,
                    N, K, lda, ldb, ldc, blockIdx.x, blockIdx.y);
  (void)M;
}

// ---------------------------------------------------------------------------
// FUSED dispatch (verified R15/R17, 512 blocks): q_b(rope) + ABSORB + krope.
// ---------------------------------------------------------------------------
__global__ __launch_bounds__(512, 2)
void fused_qba(const bf16* __restrict__ q_a_bf, const bf16* __restrict__ wqb,
               bf16* __restrict__ q2,
               const bf16* __restrict__ kv_cat, const bf16* __restrict__ wabs,
               bf16* __restrict__ k2, bf16* __restrict__ kv_vT,
               const float* __restrict__ cosp, const float* __restrict__ sinp)
{
  __shared__ unsigned short As[2][256 * 64];
  __shared__ unsigned short Bs[2][256 * 64];
  const int f = blockIdx.x;
  if (f < 192) {                       // q_b + rope epilogue (grid 24x8)
    mg3_core<bf16, 2>(As, Bs, q_a_bf, wqb, q2, q2, cosp, sinp,
                      H * QKH, QL, QL, QL, CAT2, f % 24, f / 24);
  } else if (f < 448) {                // absorb (grid 32x8)
    const int ff = f - 192;
    mg3_core<bf16, 1>(As, Bs, kv_cat, wabs, k2, kv_vT, nullptr, nullptr,
                      H * (NOPE + VH), KVL, CAT, KVL, 0, ff % 32, ff / 32);
  } else {                             // krope: k2[h][s][128..191] = kv_cat[s][512..575]
    const int base = (f - 448) * 512 + threadIdx.x;   // 0..32767
#pragma unroll
    for (int it = 0; it < 16; ++it) {
      const int idx = base + it * 32768;              // 0..524287 (uint4 units)
      const int i8 = idx & 7;
      const int hh = (idx >> 3) & 31;
      const int s  = idx >> 8;
      *(uint4*)(k2 + ((long long)hh * S + s) * CAT2 + NOPE + i8 * 8) =
          *(const uint4*)(kv_cat + (long long)s * CAT + KVL + i8 * 8);
    }
  }
}

// ---------------------------------------------------------------------------
// FUSED norm dispatch (verified R16/R17): rmsnorm + kvpost + w_q_b cast.
// ---------------------------------------------------------------------------
__global__ __launch_bounds__(256)
void fused_norm(const float* __restrict__ qkv_p,
                const float* __restrict__ g_q_a, bf16* __restrict__ q_a_bf,
                const float* __restrict__ g_kv_a,
                const float* __restrict__ cosp, const float* __restrict__ sinp,
                bf16* __restrict__ kv_cat,
                const float* __restrict__ w_q_b, bf16* __restrict__ wqb_b,
                long long poff)
{
  const int b = blockIdx.x;
  __shared__ float red[4];
  if (b < 2048) {
    const int row = b;
    const float* xr = qkv_p + (long long)row * NCAT;
    float v[6];
    float ss = 0.f;
#pragma unroll
    for (int k = 0; k < 6; k++) {
      const int c = threadIdx.x + (k << 8);
      const float t = xr[c] + xr[c + poff] + xr[c + 2 * poff] + xr[c + 3 * poff];
      v[k] = t; ss += t * t;
    }
    ss = wave_sum(ss);
    if ((threadIdx.x & 63) == 0) red[threadIdx.x >> 6] = ss;
    __syncthreads();
    const float inv = rsqrtf((red[0] + red[1] + red[2] + red[3]) / (float)QL + EPS);
#pragma unroll
    for (int k = 0; k < 6; k++) {
      const int c = threadIdx.x + (k << 8);
      q_a_bf[(long long)row * QL + c] = __float2bfloat16(v[k] * inv * g_q_a[c]);
    }
  } else if (b < 4096) {
    const int s = b - 2048;
    const float* row = qkv_p + (long long)s * NCAT + QL;
    float v[2];
    float ss = 0.f;
#pragma unroll
    for (int k = 0; k < 2; k++) {
      const int c = threadIdx.x + (k << 8);
      const float t = row[c] + row[c + poff] + row[c + 2 * poff] + row[c + 3 * poff];
      v[k] = t; ss += t * t;
    }
    float ws_ = wave_sum(ss);
    if ((threadIdx.x & 63) == 0) red[threadIdx.x >> 6] = ws_;
    __syncthreads();
    const float inv = rsqrtf((red[0] + red[1] + red[2] + red[3]) / (float)KVL + EPS);
#pragma unroll
    for (int k = 0; k < 2; k++) {
      const int c = threadIdx.x + (k << 8);
      kv_cat[(long long)s * CAT + c] = __float2bfloat16(v[k] * inv * g_kv_a[c]);
    }
    if (threadIdx.x < 64) {
      const int r = threadIdx.x;
      const int c = KVL + r;
      const float x = row[c] + row[c + poff] + row[c + 2 * poff] + row[c + 3 * poff];
      const float xp = __shfl_xor(x, 32, 64);
      const float rot = (r < 32) ? -xp : xp;
      kv_cat[(long long)s * CAT + KVL + r] =
          __float2bfloat16(x * cosp[s * ROPE + r] + rot * sinp[s * ROPE + r]);
    }
  } else {
    cast_seg(w_q_b, wqb_b, (long long)H * QKH * QL / 4, b - 4096, 256);
  }
}

// ---------------------------------------------------------------------------
// MFMA flash attention v13 (verified R4-R17, ~82 us).
// ---------------------------------------------------------------------------
__global__ __launch_bounds__(512, 2)
void attn_mfma13(const bf16* __restrict__ q2, const bf16* __restrict__ k2,
                 const bf16* __restrict__ kv_vT, bf16* __restrict__ ctx)
{
  __shared__ unsigned short kkl[2][32 * CAT2];  // 2 x 12,288 B  K tiles (swizzled)
  __shared__ unsigned short vtl[2][128 * 32];   // 2 x  8,192 B  V^T tiles (swizzled)
  __shared__ unsigned short ps[8][16][40];      // 10,240 B per-wave P transpose
  const int tid = threadIdx.x;
  const int bid = blockIdx.x;
  const int h  = bid & 31;
  const int qb = 15 - (bid >> 5);               // heavy blocks dispatched first
  const int w = tid >> 6, lane = tid & 63;
  const int l15 = lane & 15, g = lane >> 4;
  const int wq0 = qb * 128 + w * 16;
  const int rbase = g * 4;
  const float scale = 0.07216878364870322f;     // 1/sqrt(192)

  const bf16* ksrc[2];
#pragma unroll
  for (int j = 0; j < 2; j++) {
    const int f  = j * 512 + ((j == 1) ? (tid & 255) : tid);
    const int r  = f / 24;
    const int cg = ((f % 24) << 4) ^ ((r & 7) << 4);
    ksrc[j] = k2 + ((long long)h * S + r) * CAT2 + (cg >> 1);
  }
  const int vc = tid >> 2;
  const bf16* vsrc = kv_vT + (long long)h * VH * S + (long long)vc * S
                   + (((tid & 3) ^ ((vc >> 1) & 3)) * 8);

  auto stage = [&](int buf, int kbase) {
    gload16(ksrc[0] + (long long)kbase * CAT2, &kkl[buf][(w * 64) * 8]);
    if (tid < 256)
      gload16(ksrc[1] + (long long)kbase * CAT2, &kkl[buf][(512 + w * 64) * 8]);
    gload16(vsrc + kbase, &vtl[buf][(w * 64) * 8]);
  };

  s16x8 qf[6];
  const bf16* qp = q2 + ((long long)h * S + (wq0 + l15)) * CAT2 + g * 8;
#pragma unroll
  for (int ch = 0; ch < 6; ch++) qf[ch] = *(const s16x8*)(qp + ch * 32);

  s16x8 ones;
#pragma unroll
  for (int i = 0; i < 8; i++) ones[i] = (short)0x3F80;

  f32x4 acc[8];
#pragma unroll
  for (int nt = 0; nt < 8; nt++) acc[nt] = (f32x4){0.f, 0.f, 0.f, 0.f};
  f32x4 accl = (f32x4){0.f, 0.f, 0.f, 0.f};
  float mrow[4];
#pragma unroll
  for (int r = 0; r < 4; r++) mrow[r] = -3e38f;

  stage(0, 0);
  __syncthreads();

  const int ntb = 4 * qb + 4;
  int buf = 0;
  for (int t = 0; t < ntb; t++) {
    const int kbase = t * 32;
    if (t + 1 < ntb) stage(buf ^ 1, kbase + 32);   // overlap with compute(t)
    if (kbase <= wq0 + 15) {
      f32x4 st0 = (f32x4){0.f,0.f,0.f,0.f}, st1 = (f32x4){0.f,0.f,0.f,0.f};
      const unsigned short* kb0 = &kkl[buf][l15 * CAT2];
      const int rsw = (l15 & 7) << 4;
#pragma unroll
      for (int ch = 0; ch < 6; ch++) {
        const int cb = ((ch * 64 + g * 16) ^ rsw) >> 1;
        s16x8 b0 = *(const s16x8*)(kb0 + cb);
        s16x8 b1 = *(const s16x8*)(kb0 + 16 * CAT2 + cb);
        st0 = __builtin_amdgcn_mfma_f32_16x16x32_bf16(qf[ch], b0, st0, 0, 0, 0);
        st1 = __builtin_amdgcn_mfma_f32_16x16x32_bf16(qf[ch], b1, st1, 0, 0, 0);
      }
      float p0v[4], p1v[4];
      float pmax = 0.f;
#pragma unroll
      for (int r = 0; r < 4; r++) {
        const int qg = wq0 + rbase + r;
        const bool v0 = (kbase + l15) <= qg, v1 = (kbase + 16 + l15) <= qg;
        const float s0 = st0[r] * scale, s1 = st1[r] * scale;
        const float p0 = v0 ? __expf(s0 - mrow[r]) : 0.f;
        const float p1 = v1 ? __expf(s1 - mrow[r]) : 0.f;
        p0v[r] = p0; p1v[r] = p1;
        pmax = fmaxf(pmax, fmaxf(p0, p1));
      }
      if (__builtin_expect(__any(pmax > 2981.0f), 0)) {   // rare: growth > ~8
#pragma unroll
        for (int r = 0; r < 4; r++) {
          const int qg = wq0 + rbase + r;
          const bool v0 = (kbase + l15) <= qg, v1 = (kbase + 16 + l15) <= qg;
          const float s0 = st0[r] * scale, s1 = st1[r] * scale;
          float tmax = fmaxf(v0 ? s0 : -3e38f, v1 ? s1 : -3e38f);
#pragma unroll
          for (int off = 8; off; off >>= 1) tmax = fmaxf(tmax, __shfl_xor(tmax, off, 64));
          if (tmax > mrow[r] + 8.0f) {
            const float corr = __expf(mrow[r] - tmax);    // 0 on first tile
            mrow[r] = tmax;
#pragma unroll
            for (int nt = 0; nt < 8; nt++) acc[nt][r] *= corr;
            accl[r] *= corr;
            p0v[r] = v0 ? __expf(s0 - mrow[r]) : 0.f;
            p1v[r] = v1 ? __expf(s1 - mrow[r]) : 0.f;
          }
        }
      }
#pragma unroll
      for (int r = 0; r < 4; r++) {
        union { bf16 b; unsigned short u; } c0, c1;
        c0.b = __float2bfloat16(p0v[r]); c1.b = __float2bfloat16(p1v[r]);
        ps[w][rbase + r][l15]      = c0.u;
        ps[w][rbase + r][16 + l15] = c1.u;
      }
      asm volatile("" ::: "memory");   // order ps stores before reads (per-wave)
      s16x8 pa = *(const s16x8*)&ps[w][l15][g * 8];
      const unsigned short* vt = &vtl[buf][l15 * 32 + ((g * 8) ^ (((l15 >> 1) & 3) * 8))];
#pragma unroll
      for (int nt = 0; nt < 8; nt++) {
        s16x8 bv = *(const s16x8*)(vt + nt * 512);
        acc[nt] = __builtin_amdgcn_mfma_f32_16x16x32_bf16(pa, bv, acc[nt], 0, 0, 0);
      }
      accl = __builtin_amdgcn_mfma_f32_16x16x32_bf16(pa, ones, accl, 0, 0, 0);
    }
    __syncthreads();   // drains stage(t+1) loads + all waves done with buf
    buf ^= 1;
  }

#pragma unroll
  for (int r = 0; r < 4; r++) {
    const float inv = 1.f / accl[r];
    bf16* op = ctx + (long long)(wq0 + rbase + r) * (H * VH) + h * VH + l15;
#pragma unroll
    for (int nt = 0; nt < 8; nt++) op[nt * 16] = __float2bfloat16(acc[nt][r] * inv);
  }
}

// ---------------------------------------------------------------------------
extern "C" void kernel_launch(void* const* d_in, const int* in_sizes, int n_in,
                              void* d_out, int out_size, void* d_ws, size_t ws_size,
                              hipStream_t stream)
{
  const float* h2     = (const float*)d_in[0];
  const float* cosp   = (const float*)d_in[1];
  const float* sinp   = (const float*)d_in[2];
  const float* w_q_a  = (const float*)d_in[3];
  const float* g_q_a  = (const float*)d_in[4];
  const float* w_q_b  = (const float*)d_in[5];
  const float* w_kv_a = (const float*)d_in[6];
  const float* g_kv_a = (const float*)d_in[7];
  const float* w_uk_t = (const float*)d_in[8];
  const float* w_uv   = (const float*)d_in[9];
  const float* w_o    = (const float*)d_in[10];
  float* out = (float*)d_out;

  // ---- workspace layout (identical to R15-R17, which passed) ----
  char* ws = (char*)d_ws;
  bf16* wukb   = (bf16*)(ws);                          // 4,194,304  [H][NOPE][KVL]
  bf16* wuv_t  = (bf16*)(ws + 4194304);                // 4,194,304  [H][VH][KVL] (contiguous)
  bf16* kv_cat = (bf16*)(ws + 8388608);                // 2,359,296
  char* X = ws + 13107200;                             // 75,497,472
  char* Y = X + 75497472;                              // 67,108,864
  float* qkv_p = (float*)(X);                          // [4][2048][2112] f32 69,206,016
  bf16*  wo_b  = (bf16*)(X);                           // 33,554,432 (cast after fused_norm)
  bf16*  q2    = (bf16*)(X + 33554432);                // 25,165,824
  bf16*  ctx   = (bf16*)(X + 58720256);                // 16,777,216 (attn output)
  bf16*  hb     = (bf16*)(Y);                          // 16,777,216 (dead after qkv GEMM)
  bf16*  wcat_b = (bf16*)(Y + 16777216);               // 17,301,504 (dead after qkv)
  bf16*  wqb_b  = (bf16*)(Y);                          // 18,874,368 (cast in fused_norm)
  bf16*  q_a_bf = (bf16*)(Y + 18874368);               // 6,291,456
  bf16*  k2     = (bf16*)(Y + 25165824);               // 25,165,824
  bf16*  kv_vT  = (bf16*)(Y + 50331648);               // 16,777,216
  float* out_p1 = (float*)(Y);                         // 33,554,432 (after attn)

  // 0. ALL pre-GEMM casts in one dispatch
  cast_all<<<dim3(3216), dim3(256), 0, stream>>>(
      h2, hb, w_q_a, w_kv_a, wcat_b, w_uk_t, wukb, w_uv, wuv_t);

  // 1+4 merged: qkv partials = hb @ wcat_b^T, mgemm3 256² K-split z=4
  mgemm3<float><<<dim3(9, 8, 4), 512, 0, stream>>>(
      hb, wcat_b, qkv_p, qkv_p, nullptr, nullptr, S, NCAT, D / 4, D, D, NCAT,
      (long long)(D / 4), (long long)(D / 4), (long long)S * NCAT);

  // 2+5 + wqb-cast in one dispatch
  fused_norm<<<dim3(4352), dim3(256), 0, stream>>>(
      qkv_p, g_q_a, q_a_bf, g_kv_a, cosp, sinp, kv_cat, w_q_b, wqb_b,
      (long long)S * NCAT);

  // w_o cast: standalone full-machine dispatch
  cast_kernel<<<1024, 256, 0, stream>>>(w_o, wo_b, (long long)D * H * VH / 4);

  // 3+6 + 5b+7 + 7b FUSED: q_b(rope) + ABSORB + krope
  fused_qba<<<dim3(512), dim3(512), 0, stream>>>(
      q_a_bf, wqb_b, q2, kv_cat, (const bf16*)ws, k2, kv_vT, cosp, sinp);

  // 8. attention (verified v13) -> ctx bf16 [s][h*128+v]
  attn_mfma13<<<dim3(512), dim3(512), 0, stream>>>(q2, k2, kv_vT, ctx);

  // 10. out = ctx @ w_o^T -> f32, mgemm3 256² K-split z=2
  const long long ooff = (long long)(out_p1 - out);
  mgemm3<float><<<dim3(16, 8, 2), 512, 0, stream>>>(
      ctx, wo_b, out, out, nullptr, nullptr, S, D, D / 2, D, D, D,
      (long long)(D / 2), (long long)(D / 2), ooff);
  // 10b. combine: out += out_p1
  add_kernel<<<1024, 256, 0, stream>>>(out, out_p1, (long long)S * D / 4);

  (void)in_sizes; (void)n_in; (void)out_size; (void)ws_size;
}

// Round 19
// 383.897 us; speedup vs baseline: 1.0506x; 1.0506x over previous
//
#include <hip/hip_runtime.h>
#include <hip/hip_bf16.h>

typedef __hip_bfloat16 bf16;
typedef __attribute__((ext_vector_type(8))) short  s16x8;  // 8 bf16 = 4 VGPR (MFMA A/B frag)
typedef __attribute__((ext_vector_type(4))) float  f32x4;  // MFMA C/D frag

static constexpr int S    = 2048;
static constexpr int D    = 4096;
static constexpr int H    = 32;
static constexpr int QL   = 1536;
static constexpr int KVL  = 512;
static constexpr int NOPE = 128;
static constexpr int ROPE = 64;
static constexpr int QKH  = 192;
static constexpr int VH   = 128;
static constexpr int CAT  = 576;
static constexpr int CAT2 = 192;    // absorbed head dim: 128 nope + 64 rope
static constexpr int NCAT = 2112;   // QL + CAT (merged q_a/kv_a GEMM width)
static constexpr float EPS = 1e-6f;

__device__ __forceinline__ void stf(float* p, float v){ *p = v; }
__device__ __forceinline__ void stf(bf16* p, float v){ *p = __float2bfloat16(v); }

__device__ __forceinline__ float wave_sum(float v){
#pragma unroll
  for (int off = 32; off; off >>= 1) v += __shfl_xor(v, off, 64);
  return v;
}

__device__ __forceinline__ void gload16(const bf16* src, unsigned short* dst){
  __builtin_amdgcn_global_load_lds(
      (const __attribute__((address_space(1))) unsigned int*)src,
      (__attribute__((address_space(3))) unsigned int*)dst, 16, 0, 0);
}

// grid-strided f32->bf16 cast segment (256-thread blocks)
__device__ __forceinline__ void cast_seg(const float* __restrict__ in,
                                         bf16* __restrict__ out, long long n4,
                                         int brel, int nblk)
{
  long long i = (long long)brel * 256 + threadIdx.x;
  const long long stride = (long long)nblk * 256;
  for (; i < n4; i += stride) {
    float4 v = ((const float4*)in)[i];
    union { bf16 b[4]; uint2 u; } t;
    t.b[0] = __float2bfloat16(v.x); t.b[1] = __float2bfloat16(v.y);
    t.b[2] = __float2bfloat16(v.z); t.b[3] = __float2bfloat16(v.w);
    *(uint2*)(out + i * 4) = t.u;
  }
}

// ---------------------------------------------------------------------------
// standalone f32->bf16 cast (full-machine BW; used for w_o)
// ---------------------------------------------------------------------------
__global__ __launch_bounds__(256)
void cast_kernel(const float* __restrict__ in, bf16* __restrict__ out, long long n4)
{
  cast_seg(in, out, n4, blockIdx.x, gridDim.x);
}

// ---------------------------------------------------------------------------
// cast_all (verified R16/R17): ALL pre-GEMM casts in one dispatch.
// ---------------------------------------------------------------------------
__global__ __launch_bounds__(256)
void cast_all(const float* __restrict__ h2, bf16* __restrict__ hb,
              const float* __restrict__ w_q_a, const float* __restrict__ w_kv_a,
              bf16* __restrict__ wcat_b,
              const float* __restrict__ w_uk, bf16* __restrict__ wukb,
              const float* __restrict__ w_uv, bf16* __restrict__ wuv_t)
{
  const int b = blockIdx.x;
  if (b < 512) {
    cast_seg(h2, hb, (long long)S * D / 4, b, 512);
  } else if (b < 896) {
    cast_seg(w_q_a, wcat_b, (long long)QL * D / 4, b - 512, 384);
  } else if (b < 1040) {
    cast_seg(w_kv_a, wcat_b + (long long)QL * D, (long long)CAT * D / 4, b - 896, 144);
  } else if (b < 1168) {
    cast_seg(w_uk, wukb, (long long)H * NOPE * KVL / 4, b - 1040, 128);
  } else {
    // wuv tcast: in f32 [H][KVL][VH] -> out bf16 [H][VH][KVL], 32x32 tiles
    const int t2 = b - 1168;                 // 0..2047 = (VH/32) x (KVL/32) x H
    const int bx = t2 & 3, by = (t2 >> 2) & 15, bz = t2 >> 6;
    const float* in = w_uv + (long long)bz * KVL * VH;
    bf16* out = wuv_t + (long long)bz * KVL * VH;
    const int c0 = bx * 32, r0 = by * 32;
    __shared__ float t[32][33];
    const int tx = threadIdx.x & 31, ty = threadIdx.x >> 5;
#pragma unroll
    for (int p = 0; p < 4; p++)
      t[ty + p * 8][tx] = in[(long long)(r0 + ty + p * 8) * VH + c0 + tx];
    __syncthreads();
#pragma unroll
    for (int p = 0; p < 4; p++)
      out[(long long)(c0 + ty + p * 8) * KVL + r0 + tx] = __float2bfloat16(t[tx][ty + p * 8]);
  }
}

// ---------------------------------------------------------------------------
// f32 add: dst += src (K-split combine for the out GEMM)
// ---------------------------------------------------------------------------
__global__ __launch_bounds__(256)
void add_kernel(float* __restrict__ dst, const float* __restrict__ src, long long n4)
{
  long long i = (long long)blockIdx.x * 256 + threadIdx.x;
  const long long stride = (long long)gridDim.x * 256;
  for (; i < n4; i += stride) {
    float4 a = ((const float4*)dst)[i];
    const float4 b = ((const float4*)src)[i];
    a.x += b.x; a.y += b.y; a.z += b.z; a.w += b.w;
    ((float4*)dst)[i] = a;
  }
}

// ---------------------------------------------------------------------------
// mgemm3 CORE (verified R10-R17 body, RESTORED -- R18's phase-lite interleave
// regressed 86->90 us / MfmaUtil 25.5->23.5: a partial phase-split without
// the full 8-phase structure serializes VMEM issue into the MFMA stream,
// the m196 failure mode): 256x256 tile, BK=64, 8 waves, counted-vmcnt deep
// pipeline.  Monolithic 8-load stage burst + s_waitcnt vmcnt(8) keeps the
// NEXT tile's loads in flight ACROSS the barrier.
// EPI=0 plain / EPI=1 ABSORB / EPI=2 q2-ROPE (all verified).
// ---------------------------------------------------------------------------
template<typename TC, int EPI>
__device__ __forceinline__ void mg3_core(
    unsigned short (*As)[256 * 64], unsigned short (*Bs)[256 * 64],
    const bf16* __restrict__ A, const bf16* __restrict__ B,
    TC* __restrict__ C, TC* __restrict__ C2,
    const float* __restrict__ cosp, const float* __restrict__ sinp,
    int N, int K, int lda, int ldb, int ldc, int bx, int by)
{
  const int tid = threadIdx.x;
  const int w = tid >> 6;
  const int lane = tid & 63;
  const int l15 = lane & 15, g = lane >> 4;
  const int wr = w >> 2, wc = w & 3;
  const int m0 = by * 256, n0 = bx * 256;

  const bf16* asrc[4];
  const bf16* bsrc[4];
#pragma unroll
  for (int j = 0; j < 4; j++) {
    const int f = j * 512 + tid;
    const int row = f >> 3;                 // 0..255
    const int cg = ((f & 7) ^ (row & 7)) * 8;
    asrc[j] = A + (long long)(m0 + row) * lda + cg;
    int br = n0 + row; if (br >= N) br = N - 1;
    bsrc[j] = B + (long long)br * ldb + cg;
  }

  auto stage = [&](int b, int k0) {
#pragma unroll
    for (int j = 0; j < 4; j++) {
      gload16(asrc[j] + k0, &As[b][(j * 512 + w * 64) * 8]);
      gload16(bsrc[j] + k0, &Bs[b][(j * 512 + w * 64) * 8]);
    }
  };

  f32x4 acc[8][4];
#pragma unroll
  for (int i = 0; i < 8; i++)
#pragma unroll
    for (int j = 0; j < 4; j++) acc[i][j] = (f32x4){0.f, 0.f, 0.f, 0.f};

  const int ntk = K >> 6;
  stage(0, 0);

  for (int t = 0; t < ntk; ++t) {
    const int b = t & 1;
    asm volatile("" ::: "memory");
    __builtin_amdgcn_s_barrier();
    if (t + 1 < ntk) {
      stage(b ^ 1, (t + 1) << 6);
      asm volatile("s_waitcnt vmcnt(8)" ::: "memory");
    } else {
      asm volatile("s_waitcnt vmcnt(0)" ::: "memory");
    }
    __builtin_amdgcn_s_barrier();
    asm volatile("" ::: "memory");

    const unsigned short* Ab = &As[b][(wr * 128 + l15) * 64];
    const unsigned short* Bb = &Bs[b][(wc * 64 + l15) * 64];
    const int swz = l15 & 7;
#pragma unroll
    for (int kk = 0; kk < 2; ++kk) {
      const int co = (((kk * 4 + g) ^ swz) * 8);
      s16x8 a[8], bb[4];
#pragma unroll
      for (int mt = 0; mt < 8; mt++)
        a[mt] = *(const s16x8*)(Ab + mt * 1024 + co);
#pragma unroll
      for (int nt = 0; nt < 4; nt++)
        bb[nt] = *(const s16x8*)(Bb + nt * 1024 + co);
      __builtin_amdgcn_s_setprio(1);
#pragma unroll
      for (int mt = 0; mt < 8; mt++)
#pragma unroll
        for (int nt = 0; nt < 4; nt++)
          acc[mt][nt] = __builtin_amdgcn_mfma_f32_16x16x32_bf16(a[mt], bb[nt], acc[mt][nt], 0, 0, 0);
      __builtin_amdgcn_s_setprio(0);
    }
  }

  if constexpr (EPI == 2) {
    const int blk = bx * 4 + wc;
    const int hh = blk / 3;
    const int dbase = (blk % 3) * 64;
    const bool isrope = (dbase == 128);
#pragma unroll
    for (int mt = 0; mt < 8; mt++) {
      const int row0 = m0 + wr * 128 + mt * 16 + g * 4;
#pragma unroll
      for (int nt = 0; nt < 4; nt++) {
        if (!isrope) {
          const int d = dbase + nt * 16 + l15;
#pragma unroll
          for (int r = 0; r < 4; r++)
            stf((bf16*)C + ((long long)hh * S + row0 + r) * CAT2 + d, acc[mt][nt][r]);
        } else {
          const int rr = nt * 16 + l15;     // rope dim 0..63
#pragma unroll
          for (int r = 0; r < 4; r++) {
            const int srow = row0 + r;
            const float x   = acc[mt][nt][r];
            const float xp  = acc[mt][nt ^ 2][r];     // col +/- 32, in-register
            const float rot = (rr < 32) ? -xp : xp;
            stf((bf16*)C + ((long long)hh * S + srow) * CAT2 + NOPE + rr,
                x * cosp[srow * ROPE + rr] + rot * sinp[srow * ROPE + rr]);
          }
        }
      }
    }
  } else {
#pragma unroll
    for (int mt = 0; mt < 8; mt++)
#pragma unroll
      for (int nt = 0; nt < 4; nt++) {
        const int col = n0 + wc * 64 + nt * 16 + l15;
        const int row0 = m0 + wr * 128 + mt * 16 + g * 4;
        if constexpr (EPI == 0) {
          if (col < N) {
#pragma unroll
            for (int r = 0; r < 4; r++)
              stf(C + (long long)(row0 + r) * ldc + col, acc[mt][nt][r]);
          }
        } else {
          if (col < H * NOPE) {               // key-absorb -> k2[h][row][n]
            TC* dst = C + ((long long)(col >> 7) * S + row0) * CAT2 + (col & 127);
#pragma unroll
            for (int r = 0; r < 4; r++)
              stf(dst + (long long)r * CAT2, acc[mt][nt][r]);
          } else {                             // value-absorb -> kv_vT[c'][row]
            TC* dst = C2 + (long long)(col - H * NOPE) * S + row0;
#pragma unroll
            for (int r = 0; r < 4; r++)
              stf(dst + r, acc[mt][nt][r]);
          }
        }
      }
  }
}

// ---------------------------------------------------------------------------
// standalone mgemm3 (qkv, out GEMMs): z-batch/K-split plumbing + core
// ---------------------------------------------------------------------------
template<typename TC, int EPI = 0>
__global__ __launch_bounds__(512, 2)
void mgemm3(const bf16* __restrict__ A, const bf16* __restrict__ B, TC* __restrict__ C,
            TC* __restrict__ C2, const float* __restrict__ cosp,
            const float* __restrict__ sinp,
            int M, int N, int K, int lda, int ldb, int ldc,
            long long sA, long long sB, long long sC)
{
  A += (long long)blockIdx.z * sA;
  B += (long long)blockIdx.z * sB;
  C += (long long)blockIdx.z * sC;
  __shared__ unsigned short As[2][256 * 64];   // 2 x 32 KB
  __shared__ unsigned short Bs[2][256 * 64];   // 2 x 32 KB
  mg3_core<TC, EPI>(As, Bs, A, B, C, C2, cosp, sinp,
                    N, K, lda, ldb, ldc, blockIdx.x, blockIdx.y);
  (void)M;
}

// ---------------------------------------------------------------------------
// FUSED dispatch (verified R15/R17, 512 blocks): q_b(rope) + ABSORB + krope.
// ---------------------------------------------------------------------------
__global__ __launch_bounds__(512, 2)
void fused_qba(const bf16* __restrict__ q_a_bf, const bf16* __restrict__ wqb,
               bf16* __restrict__ q2,
               const bf16* __restrict__ kv_cat, const bf16* __restrict__ wabs,
               bf16* __restrict__ k2, bf16* __restrict__ kv_vT,
               const float* __restrict__ cosp, const float* __restrict__ sinp)
{
  __shared__ unsigned short As[2][256 * 64];
  __shared__ unsigned short Bs[2][256 * 64];
  const int f = blockIdx.x;
  if (f < 192) {                       // q_b + rope epilogue (grid 24x8)
    mg3_core<bf16, 2>(As, Bs, q_a_bf, wqb, q2, q2, cosp, sinp,
                      H * QKH, QL, QL, QL, CAT2, f % 24, f / 24);
  } else if (f < 448) {                // absorb (grid 32x8)
    const int ff = f - 192;
    mg3_core<bf16, 1>(As, Bs, kv_cat, wabs, k2, kv_vT, nullptr, nullptr,
                      H * (NOPE + VH), KVL, CAT, KVL, 0, ff % 32, ff / 32);
  } else {                             // krope: k2[h][s][128..191] = kv_cat[s][512..575]
    const int base = (f - 448) * 512 + threadIdx.x;   // 0..32767
#pragma unroll
    for (int it = 0; it < 16; ++it) {
      const int idx = base + it * 32768;              // 0..524287 (uint4 units)
      const int i8 = idx & 7;
      const int hh = (idx >> 3) & 31;
      const int s  = idx >> 8;
      *(uint4*)(k2 + ((long long)hh * S + s) * CAT2 + NOPE + i8 * 8) =
          *(const uint4*)(kv_cat + (long long)s * CAT + KVL + i8 * 8);
    }
  }
}

// ---------------------------------------------------------------------------
// FUSED norm dispatch (verified R16/R17): rmsnorm + kvpost + w_q_b cast.
// ---------------------------------------------------------------------------
__global__ __launch_bounds__(256)
void fused_norm(const float* __restrict__ qkv_p,
                const float* __restrict__ g_q_a, bf16* __restrict__ q_a_bf,
                const float* __restrict__ g_kv_a,
                const float* __restrict__ cosp, const float* __restrict__ sinp,
                bf16* __restrict__ kv_cat,
                const float* __restrict__ w_q_b, bf16* __restrict__ wqb_b,
                long long poff)
{
  const int b = blockIdx.x;
  __shared__ float red[4];
  if (b < 2048) {
    const int row = b;
    const float* xr = qkv_p + (long long)row * NCAT;
    float v[6];
    float ss = 0.f;
#pragma unroll
    for (int k = 0; k < 6; k++) {
      const int c = threadIdx.x + (k << 8);
      const float t = xr[c] + xr[c + poff] + xr[c + 2 * poff] + xr[c + 3 * poff];
      v[k] = t; ss += t * t;
    }
    ss = wave_sum(ss);
    if ((threadIdx.x & 63) == 0) red[threadIdx.x >> 6] = ss;
    __syncthreads();
    const float inv = rsqrtf((red[0] + red[1] + red[2] + red[3]) / (float)QL + EPS);
#pragma unroll
    for (int k = 0; k < 6; k++) {
      const int c = threadIdx.x + (k << 8);
      q_a_bf[(long long)row * QL + c] = __float2bfloat16(v[k] * inv * g_q_a[c]);
    }
  } else if (b < 4096) {
    const int s = b - 2048;
    const float* row = qkv_p + (long long)s * NCAT + QL;
    float v[2];
    float ss = 0.f;
#pragma unroll
    for (int k = 0; k < 2; k++) {
      const int c = threadIdx.x + (k << 8);
      const float t = row[c] + row[c + poff] + row[c + 2 * poff] + row[c + 3 * poff];
      v[k] = t; ss += t * t;
    }
    float ws_ = wave_sum(ss);
    if ((threadIdx.x & 63) == 0) red[threadIdx.x >> 6] = ws_;
    __syncthreads();
    const float inv = rsqrtf((red[0] + red[1] + red[2] + red[3]) / (float)KVL + EPS);
#pragma unroll
    for (int k = 0; k < 2; k++) {
      const int c = threadIdx.x + (k << 8);
      kv_cat[(long long)s * CAT + c] = __float2bfloat16(v[k] * inv * g_kv_a[c]);
    }
    if (threadIdx.x < 64) {
      const int r = threadIdx.x;
      const int c = KVL + r;
      const float x = row[c] + row[c + poff] + row[c + 2 * poff] + row[c + 3 * poff];
      const float xp = __shfl_xor(x, 32, 64);
      const float rot = (r < 32) ? -xp : xp;
      kv_cat[(long long)s * CAT + KVL + r] =
          __float2bfloat16(x * cosp[s * ROPE + r] + rot * sinp[s * ROPE + r]);
    }
  } else {
    cast_seg(w_q_b, wqb_b, (long long)H * QKH * QL / 4, b - 4096, 256);
  }
}

// ---------------------------------------------------------------------------
// MFMA flash attention v13 (verified R4-R17, ~82 us): key+value absorbed,
// head dim 192, cheap overflow-detect softmax, stage-before-compute +
// single __syncthreads skeleton.
// ---------------------------------------------------------------------------
__global__ __launch_bounds__(512, 2)
void attn_mfma13(const bf16* __restrict__ q2, const bf16* __restrict__ k2,
                 const bf16* __restrict__ kv_vT, bf16* __restrict__ ctx)
{
  __shared__ unsigned short kkl[2][32 * CAT2];  // 2 x 12,288 B  K tiles (swizzled)
  __shared__ unsigned short vtl[2][128 * 32];   // 2 x  8,192 B  V^T tiles (swizzled)
  __shared__ unsigned short ps[8][16][40];      // 10,240 B per-wave P transpose
  const int tid = threadIdx.x;
  const int bid = blockIdx.x;
  const int h  = bid & 31;
  const int qb = 15 - (bid >> 5);               // heavy blocks dispatched first
  const int w = tid >> 6, lane = tid & 63;
  const int l15 = lane & 15, g = lane >> 4;
  const int wq0 = qb * 128 + w * 16;
  const int rbase = g * 4;
  const float scale = 0.07216878364870322f;     // 1/sqrt(192)

  const bf16* ksrc[2];
#pragma unroll
  for (int j = 0; j < 2; j++) {
    const int f  = j * 512 + ((j == 1) ? (tid & 255) : tid);
    const int r  = f / 24;
    const int cg = ((f % 24) << 4) ^ ((r & 7) << 4);
    ksrc[j] = k2 + ((long long)h * S + r) * CAT2 + (cg >> 1);
  }
  const int vc = tid >> 2;
  const bf16* vsrc = kv_vT + (long long)h * VH * S + (long long)vc * S
                   + (((tid & 3) ^ ((vc >> 1) & 3)) * 8);

  auto stage = [&](int buf, int kbase) {
    gload16(ksrc[0] + (long long)kbase * CAT2, &kkl[buf][(w * 64) * 8]);
    if (tid < 256)
      gload16(ksrc[1] + (long long)kbase * CAT2, &kkl[buf][(512 + w * 64) * 8]);
    gload16(vsrc + kbase, &vtl[buf][(w * 64) * 8]);
  };

  s16x8 qf[6];
  const bf16* qp = q2 + ((long long)h * S + (wq0 + l15)) * CAT2 + g * 8;
#pragma unroll
  for (int ch = 0; ch < 6; ch++) qf[ch] = *(const s16x8*)(qp + ch * 32);

  s16x8 ones;
#pragma unroll
  for (int i = 0; i < 8; i++) ones[i] = (short)0x3F80;

  f32x4 acc[8];
#pragma unroll
  for (int nt = 0; nt < 8; nt++) acc[nt] = (f32x4){0.f, 0.f, 0.f, 0.f};
  f32x4 accl = (f32x4){0.f, 0.f, 0.f, 0.f};
  float mrow[4];
#pragma unroll
  for (int r = 0; r < 4; r++) mrow[r] = -3e38f;

  stage(0, 0);
  __syncthreads();

  const int ntb = 4 * qb + 4;
  int buf = 0;
  for (int t = 0; t < ntb; t++) {
    const int kbase = t * 32;
    if (t + 1 < ntb) stage(buf ^ 1, kbase + 32);   // overlap with compute(t)
    if (kbase <= wq0 + 15) {
      f32x4 st0 = (f32x4){0.f,0.f,0.f,0.f}, st1 = (f32x4){0.f,0.f,0.f,0.f};
      const unsigned short* kb0 = &kkl[buf][l15 * CAT2];
      const int rsw = (l15 & 7) << 4;
#pragma unroll
      for (int ch = 0; ch < 6; ch++) {
        const int cb = ((ch * 64 + g * 16) ^ rsw) >> 1;
        s16x8 b0 = *(const s16x8*)(kb0 + cb);
        s16x8 b1 = *(const s16x8*)(kb0 + 16 * CAT2 + cb);
        st0 = __builtin_amdgcn_mfma_f32_16x16x32_bf16(qf[ch], b0, st0, 0, 0, 0);
        st1 = __builtin_amdgcn_mfma_f32_16x16x32_bf16(qf[ch], b1, st1, 0, 0, 0);
      }
      float p0v[4], p1v[4];
      float pmax = 0.f;
#pragma unroll
      for (int r = 0; r < 4; r++) {
        const int qg = wq0 + rbase + r;
        const bool v0 = (kbase + l15) <= qg, v1 = (kbase + 16 + l15) <= qg;
        const float s0 = st0[r] * scale, s1 = st1[r] * scale;
        const float p0 = v0 ? __expf(s0 - mrow[r]) : 0.f;
        const float p1 = v1 ? __expf(s1 - mrow[r]) : 0.f;
        p0v[r] = p0; p1v[r] = p1;
        pmax = fmaxf(pmax, fmaxf(p0, p1));
      }
      if (__builtin_expect(__any(pmax > 2981.0f), 0)) {   // rare: growth > ~8
#pragma unroll
        for (int r = 0; r < 4; r++) {
          const int qg = wq0 + rbase + r;
          const bool v0 = (kbase + l15) <= qg, v1 = (kbase + 16 + l15) <= qg;
          const float s0 = st0[r] * scale, s1 = st1[r] * scale;
          float tmax = fmaxf(v0 ? s0 : -3e38f, v1 ? s1 : -3e38f);
#pragma unroll
          for (int off = 8; off; off >>= 1) tmax = fmaxf(tmax, __shfl_xor(tmax, off, 64));
          if (tmax > mrow[r] + 8.0f) {
            const float corr = __expf(mrow[r] - tmax);    // 0 on first tile
            mrow[r] = tmax;
#pragma unroll
            for (int nt = 0; nt < 8; nt++) acc[nt][r] *= corr;
            accl[r] *= corr;
            p0v[r] = v0 ? __expf(s0 - mrow[r]) : 0.f;
            p1v[r] = v1 ? __expf(s1 - mrow[r]) : 0.f;
          }
        }
      }
#pragma unroll
      for (int r = 0; r < 4; r++) {
        union { bf16 b; unsigned short u; } c0, c1;
        c0.b = __float2bfloat16(p0v[r]); c1.b = __float2bfloat16(p1v[r]);
        ps[w][rbase + r][l15]      = c0.u;
        ps[w][rbase + r][16 + l15] = c1.u;
      }
      asm volatile("" ::: "memory");   // order ps stores before reads (per-wave)
      s16x8 pa = *(const s16x8*)&ps[w][l15][g * 8];
      const unsigned short* vt = &vtl[buf][l15 * 32 + ((g * 8) ^ (((l15 >> 1) & 3) * 8))];
#pragma unroll
      for (int nt = 0; nt < 8; nt++) {
        s16x8 bv = *(const s16x8*)(vt + nt * 512);
        acc[nt] = __builtin_amdgcn_mfma_f32_16x16x32_bf16(pa, bv, acc[nt], 0, 0, 0);
      }
      accl = __builtin_amdgcn_mfma_f32_16x16x32_bf16(pa, ones, accl, 0, 0, 0);
    }
    __syncthreads();   // drains stage(t+1) loads + all waves done with buf
    buf ^= 1;
  }

#pragma unroll
  for (int r = 0; r < 4; r++) {
    const float inv = 1.f / accl[r];
    bf16* op = ctx + (long long)(wq0 + rbase + r) * (H * VH) + h * VH + l15;
#pragma unroll
    for (int nt = 0; nt < 8; nt++) op[nt * 16] = __float2bfloat16(acc[nt][r] * inv);
  }
}

// ---------------------------------------------------------------------------
extern "C" void kernel_launch(void* const* d_in, const int* in_sizes, int n_in,
                              void* d_out, int out_size, void* d_ws, size_t ws_size,
                              hipStream_t stream)
{
  const float* h2     = (const float*)d_in[0];
  const float* cosp   = (const float*)d_in[1];
  const float* sinp   = (const float*)d_in[2];
  const float* w_q_a  = (const float*)d_in[3];
  const float* g_q_a  = (const float*)d_in[4];
  const float* w_q_b  = (const float*)d_in[5];
  const float* w_kv_a = (const float*)d_in[6];
  const float* g_kv_a = (const float*)d_in[7];
  const float* w_uk_t = (const float*)d_in[8];
  const float* w_uv   = (const float*)d_in[9];
  const float* w_o    = (const float*)d_in[10];
  float* out = (float*)d_out;

  // ---- workspace layout (identical to R15-R17, which passed) ----
  char* ws = (char*)d_ws;
  bf16* wukb   = (bf16*)(ws);                          // 4,194,304  [H][NOPE][KVL]
  bf16* wuv_t  = (bf16*)(ws + 4194304);                // 4,194,304  [H][VH][KVL] (contiguous)
  bf16* kv_cat = (bf16*)(ws + 8388608);                // 2,359,296
  char* X = ws + 13107200;                             // 75,497,472
  char* Y = X + 75497472;                              // 67,108,864
  float* qkv_p = (float*)(X);                          // [4][2048][2112] f32 69,206,016
  bf16*  wo_b  = (bf16*)(X);                           // 33,554,432 (cast after fused_norm)
  bf16*  q2    = (bf16*)(X + 33554432);                // 25,165,824
  bf16*  ctx   = (bf16*)(X + 58720256);                // 16,777,216 (attn output)
  bf16*  hb     = (bf16*)(Y);                          // 16,777,216 (dead after qkv GEMM)
  bf16*  wcat_b = (bf16*)(Y + 16777216);               // 17,301,504 (dead after qkv)
  bf16*  wqb_b  = (bf16*)(Y);                          // 18,874,368 (cast in fused_norm)
  bf16*  q_a_bf = (bf16*)(Y + 18874368);               // 6,291,456
  bf16*  k2     = (bf16*)(Y + 25165824);               // 25,165,824
  bf16*  kv_vT  = (bf16*)(Y + 50331648);               // 16,777,216
  float* out_p1 = (float*)(Y);                         // 33,554,432 (after attn)

  // 0. ALL pre-GEMM casts in one dispatch
  cast_all<<<dim3(3216), dim3(256), 0, stream>>>(
      h2, hb, w_q_a, w_kv_a, wcat_b, w_uk_t, wukb, w_uv, wuv_t);

  // 1+4 merged: qkv partials = hb @ wcat_b^T, mgemm3 256² K-split z=4
  mgemm3<float><<<dim3(9, 8, 4), 512, 0, stream>>>(
      hb, wcat_b, qkv_p, qkv_p, nullptr, nullptr, S, NCAT, D / 4, D, D, NCAT,
      (long long)(D / 4), (long long)(D / 4), (long long)S * NCAT);

  // 2+5 + wqb-cast in one dispatch
  fused_norm<<<dim3(4352), dim3(256), 0, stream>>>(
      qkv_p, g_q_a, q_a_bf, g_kv_a, cosp, sinp, kv_cat, w_q_b, wqb_b,
      (long long)S * NCAT);

  // w_o cast: standalone full-machine dispatch
  cast_kernel<<<1024, 256, 0, stream>>>(w_o, wo_b, (long long)D * H * VH / 4);

  // 3+6 + 5b+7 + 7b FUSED: q_b(rope) + ABSORB + krope
  fused_qba<<<dim3(512), dim3(512), 0, stream>>>(
      q_a_bf, wqb_b, q2, kv_cat, (const bf16*)ws, k2, kv_vT, cosp, sinp);

  // 8. attention (verified v13) -> ctx bf16 [s][h*128+v]
  attn_mfma13<<<dim3(512), dim3(512), 0, stream>>>(q2, k2, kv_vT, ctx);

  // 10. out = ctx @ w_o^T -> f32, mgemm3 256² K-split z=2
  const long long ooff = (long long)(out_p1 - out);
  mgemm3<float><<<dim3(16, 8, 2), 512, 0, stream>>>(
      ctx, wo_b, out, out, nullptr, nullptr, S, D, D / 2, D, D, D,
      (long long)(D / 2), (long long)(D / 2), ooff);
  // 10b. combine: out += out_p1
  add_kernel<<<1024, 256, 0, stream>>>(out, out_p1, (long long)S * D / 4);

  (void)in_sizes; (void)n_in; (void)out_size; (void)ws_size;
}

// Round 20
// 360.667 us; speedup vs baseline: 1.1183x; 1.0644x over previous
//
#include <hip/hip_runtime.h>
#include <hip/hip_bf16.h>

typedef __hip_bfloat16 bf16;
typedef __attribute__((ext_vector_type(8))) short  s16x8;  // 8 bf16 = 4 VGPR (MFMA A/B frag)
typedef __attribute__((ext_vector_type(4))) float  f32x4;  // MFMA C/D frag

static constexpr int S    = 2048;
static constexpr int D    = 4096;
static constexpr int H    = 32;
static constexpr int QL   = 1536;
static constexpr int KVL  = 512;
static constexpr int NOPE = 128;
static constexpr int ROPE = 64;
static constexpr int QKH  = 192;
static constexpr int VH   = 128;
static constexpr int CAT  = 576;
static constexpr int CAT2 = 192;    // absorbed head dim: 128 nope + 64 rope
static constexpr int NCAT = 2112;   // QL + CAT (merged q_a/kv_a GEMM width)
static constexpr float EPS = 1e-6f;

__device__ __forceinline__ void stf(float* p, float v){ *p = v; }
__device__ __forceinline__ void stf(bf16* p, float v){ *p = __float2bfloat16(v); }

__device__ __forceinline__ float wave_sum(float v){
#pragma unroll
  for (int off = 32; off; off >>= 1) v += __shfl_xor(v, off, 64);
  return v;
}

__device__ __forceinline__ void gload16(const bf16* src, unsigned short* dst){
  __builtin_amdgcn_global_load_lds(
      (const __attribute__((address_space(1))) unsigned int*)src,
      (__attribute__((address_space(3))) unsigned int*)dst, 16, 0, 0);
}

// grid-strided f32->bf16 cast segment (256-thread blocks)
__device__ __forceinline__ void cast_seg(const float* __restrict__ in,
                                         bf16* __restrict__ out, long long n4,
                                         int brel, int nblk)
{
  long long i = (long long)brel * 256 + threadIdx.x;
  const long long stride = (long long)nblk * 256;
  for (; i < n4; i += stride) {
    float4 v = ((const float4*)in)[i];
    union { bf16 b[4]; uint2 u; } t;
    t.b[0] = __float2bfloat16(v.x); t.b[1] = __float2bfloat16(v.y);
    t.b[2] = __float2bfloat16(v.z); t.b[3] = __float2bfloat16(v.w);
    *(uint2*)(out + i * 4) = t.u;
  }
}

// ---------------------------------------------------------------------------
// standalone f32->bf16 cast (full-machine BW; used for w_o)
// ---------------------------------------------------------------------------
__global__ __launch_bounds__(256)
void cast_kernel(const float* __restrict__ in, bf16* __restrict__ out, long long n4)
{
  cast_seg(in, out, n4, blockIdx.x, gridDim.x);
}

// ---------------------------------------------------------------------------
// cast_all (verified R16-R19): ALL pre-GEMM casts in one dispatch.
// ---------------------------------------------------------------------------
__global__ __launch_bounds__(256)
void cast_all(const float* __restrict__ h2, bf16* __restrict__ hb,
              const float* __restrict__ w_q_a, const float* __restrict__ w_kv_a,
              bf16* __restrict__ wcat_b,
              const float* __restrict__ w_uk, bf16* __restrict__ wukb,
              const float* __restrict__ w_uv, bf16* __restrict__ wuv_t)
{
  const int b = blockIdx.x;
  if (b < 512) {
    cast_seg(h2, hb, (long long)S * D / 4, b, 512);
  } else if (b < 896) {
    cast_seg(w_q_a, wcat_b, (long long)QL * D / 4, b - 512, 384);
  } else if (b < 1040) {
    cast_seg(w_kv_a, wcat_b + (long long)QL * D, (long long)CAT * D / 4, b - 896, 144);
  } else if (b < 1168) {
    cast_seg(w_uk, wukb, (long long)H * NOPE * KVL / 4, b - 1040, 128);
  } else {
    // wuv tcast: in f32 [H][KVL][VH] -> out bf16 [H][VH][KVL], 32x32 tiles
    const int t2 = b - 1168;                 // 0..2047 = (VH/32) x (KVL/32) x H
    const int bx = t2 & 3, by = (t2 >> 2) & 15, bz = t2 >> 6;
    const float* in = w_uv + (long long)bz * KVL * VH;
    bf16* out = wuv_t + (long long)bz * KVL * VH;
    const int c0 = bx * 32, r0 = by * 32;
    __shared__ float t[32][33];
    const int tx = threadIdx.x & 31, ty = threadIdx.x >> 5;
#pragma unroll
    for (int p = 0; p < 4; p++)
      t[ty + p * 8][tx] = in[(long long)(r0 + ty + p * 8) * VH + c0 + tx];
    __syncthreads();
#pragma unroll
    for (int p = 0; p < 4; p++)
      out[(long long)(c0 + ty + p * 8) * KVL + r0 + tx] = __float2bfloat16(t[tx][ty + p * 8]);
  }
}

// ---------------------------------------------------------------------------
// f32 add: dst += src (K-split combine for the out GEMM)
// ---------------------------------------------------------------------------
__global__ __launch_bounds__(256)
void add_kernel(float* __restrict__ dst, const float* __restrict__ src, long long n4)
{
  long long i = (long long)blockIdx.x * 256 + threadIdx.x;
  const long long stride = (long long)gridDim.x * 256;
  for (; i < n4; i += stride) {
    float4 a = ((const float4*)dst)[i];
    const float4 b = ((const float4*)src)[i];
    a.x += b.x; a.y += b.y; a.z += b.z; a.w += b.w;
    ((float4*)dst)[i] = a;
  }
}

// ---------------------------------------------------------------------------
// mgemm3 CORE (verified R10-R19): 256x256 tile, BK=64, 8 waves, counted-vmcnt
// deep pipeline.  Monolithic 8-load stage burst + s_waitcnt vmcnt(8) keeps
// the NEXT tile's loads in flight ACROSS the barrier.
// EPI=0 plain / EPI=1 ABSORB / EPI=2 q2-ROPE (all verified).
// ---------------------------------------------------------------------------
template<typename TC, int EPI>
__device__ __forceinline__ void mg3_core(
    unsigned short (*As)[256 * 64], unsigned short (*Bs)[256 * 64],
    const bf16* __restrict__ A, const bf16* __restrict__ B,
    TC* __restrict__ C, TC* __restrict__ C2,
    const float* __restrict__ cosp, const float* __restrict__ sinp,
    int N, int K, int lda, int ldb, int ldc, int bx, int by)
{
  const int tid = threadIdx.x;
  const int w = tid >> 6;
  const int lane = tid & 63;
  const int l15 = lane & 15, g = lane >> 4;
  const int wr = w >> 2, wc = w & 3;
  const int m0 = by * 256, n0 = bx * 256;

  const bf16* asrc[4];
  const bf16* bsrc[4];
#pragma unroll
  for (int j = 0; j < 4; j++) {
    const int f = j * 512 + tid;
    const int row = f >> 3;                 // 0..255
    const int cg = ((f & 7) ^ (row & 7)) * 8;
    asrc[j] = A + (long long)(m0 + row) * lda + cg;
    int br = n0 + row; if (br >= N) br = N - 1;
    bsrc[j] = B + (long long)br * ldb + cg;
  }

  auto stage = [&](int b, int k0) {
#pragma unroll
    for (int j = 0; j < 4; j++) {
      gload16(asrc[j] + k0, &As[b][(j * 512 + w * 64) * 8]);
      gload16(bsrc[j] + k0, &Bs[b][(j * 512 + w * 64) * 8]);
    }
  };

  f32x4 acc[8][4];
#pragma unroll
  for (int i = 0; i < 8; i++)
#pragma unroll
    for (int j = 0; j < 4; j++) acc[i][j] = (f32x4){0.f, 0.f, 0.f, 0.f};

  const int ntk = K >> 6;
  stage(0, 0);

  for (int t = 0; t < ntk; ++t) {
    const int b = t & 1;
    asm volatile("" ::: "memory");
    __builtin_amdgcn_s_barrier();
    if (t + 1 < ntk) {
      stage(b ^ 1, (t + 1) << 6);
      asm volatile("s_waitcnt vmcnt(8)" ::: "memory");
    } else {
      asm volatile("s_waitcnt vmcnt(0)" ::: "memory");
    }
    __builtin_amdgcn_s_barrier();
    asm volatile("" ::: "memory");

    const unsigned short* Ab = &As[b][(wr * 128 + l15) * 64];
    const unsigned short* Bb = &Bs[b][(wc * 64 + l15) * 64];
    const int swz = l15 & 7;
#pragma unroll
    for (int kk = 0; kk < 2; ++kk) {
      const int co = (((kk * 4 + g) ^ swz) * 8);
      s16x8 a[8], bb[4];
#pragma unroll
      for (int mt = 0; mt < 8; mt++)
        a[mt] = *(const s16x8*)(Ab + mt * 1024 + co);
#pragma unroll
      for (int nt = 0; nt < 4; nt++)
        bb[nt] = *(const s16x8*)(Bb + nt * 1024 + co);
      __builtin_amdgcn_s_setprio(1);
#pragma unroll
      for (int mt = 0; mt < 8; mt++)
#pragma unroll
        for (int nt = 0; nt < 4; nt++)
          acc[mt][nt] = __builtin_amdgcn_mfma_f32_16x16x32_bf16(a[mt], bb[nt], acc[mt][nt], 0, 0, 0);
      __builtin_amdgcn_s_setprio(0);
    }
  }

  if constexpr (EPI == 2) {
    const int blk = bx * 4 + wc;
    const int hh = blk / 3;
    const int dbase = (blk % 3) * 64;
    const bool isrope = (dbase == 128);
#pragma unroll
    for (int mt = 0; mt < 8; mt++) {
      const int row0 = m0 + wr * 128 + mt * 16 + g * 4;
#pragma unroll
      for (int nt = 0; nt < 4; nt++) {
        if (!isrope) {
          const int d = dbase + nt * 16 + l15;
#pragma unroll
          for (int r = 0; r < 4; r++)
            stf((bf16*)C + ((long long)hh * S + row0 + r) * CAT2 + d, acc[mt][nt][r]);
        } else {
          const int rr = nt * 16 + l15;     // rope dim 0..63
#pragma unroll
          for (int r = 0; r < 4; r++) {
            const int srow = row0 + r;
            const float x   = acc[mt][nt][r];
            const float xp  = acc[mt][nt ^ 2][r];     // col +/- 32, in-register
            const float rot = (rr < 32) ? -xp : xp;
            stf((bf16*)C + ((long long)hh * S + srow) * CAT2 + NOPE + rr,
                x * cosp[srow * ROPE + rr] + rot * sinp[srow * ROPE + rr]);
          }
        }
      }
    }
  } else {
#pragma unroll
    for (int mt = 0; mt < 8; mt++)
#pragma unroll
      for (int nt = 0; nt < 4; nt++) {
        const int col = n0 + wc * 64 + nt * 16 + l15;
        const int row0 = m0 + wr * 128 + mt * 16 + g * 4;
        if constexpr (EPI == 0) {
          if (col < N) {
#pragma unroll
            for (int r = 0; r < 4; r++)
              stf(C + (long long)(row0 + r) * ldc + col, acc[mt][nt][r]);
          }
        } else {
          if (col < H * NOPE) {               // key-absorb -> k2[h][row][n]
            TC* dst = C + ((long long)(col >> 7) * S + row0) * CAT2 + (col & 127);
#pragma unroll
            for (int r = 0; r < 4; r++)
              stf(dst + (long long)r * CAT2, acc[mt][nt][r]);
          } else {                             // value-absorb -> kv_vT[c'][row]
            TC* dst = C2 + (long long)(col - H * NOPE) * S + row0;
#pragma unroll
            for (int r = 0; r < 4; r++)
              stf(dst + r, acc[mt][nt][r]);
          }
        }
      }
  }
}

// ---------------------------------------------------------------------------
// standalone mgemm3 (out GEMM): z-batch/K-split plumbing + core
// ---------------------------------------------------------------------------
template<typename TC, int EPI = 0>
__global__ __launch_bounds__(512, 2)
void mgemm3(const bf16* __restrict__ A, const bf16* __restrict__ B, TC* __restrict__ C,
            TC* __restrict__ C2, const float* __restrict__ cosp,
            const float* __restrict__ sinp,
            int M, int N, int K, int lda, int ldb, int ldc,
            long long sA, long long sB, long long sC)
{
  A += (long long)blockIdx.z * sA;
  B += (long long)blockIdx.z * sB;
  C += (long long)blockIdx.z * sC;
  __shared__ unsigned short As[2][256 * 64];   // 2 x 32 KB
  __shared__ unsigned short Bs[2][256 * 64];   // 2 x 32 KB
  mg3_core<TC, EPI>(As, Bs, A, B, C, C2, cosp, sinp,
                    N, K, lda, ldb, ldc, blockIdx.x, blockIdx.y);
  (void)M;
}

// ---------------------------------------------------------------------------
// mgemm3_k3 (qkv GEMM): UNEVEN 3-way K-split, one scheduling wave.
//   R19's z=4 ran 288 blocks at 1 block/CU -> a full 256-block wave + a
//   32-block straggler wave = 2x makespan at 12.5% utilization in wave 2.
//   z=3 -> 216 blocks = ONE wave; K = 64 tiles split 22+21+21 (kt0 0/22/43).
//   Consumers sum 3 partials (z-stride sC).  mg3_core unchanged (verified).
// ---------------------------------------------------------------------------
template<typename TC>
__global__ __launch_bounds__(512, 2)
void mgemm3_k3(const bf16* __restrict__ A, const bf16* __restrict__ B,
               TC* __restrict__ C,
               int N, int lda, int ldb, int ldc, long long sC)
{
  const int z = blockIdx.z;
  const int kt0 = z * 21 + (z > 0 ? 1 : 0);    // 0, 22, 43
  const int nt  = 21 + (z == 0 ? 1 : 0);       // 22, 21, 21  (sum = 64 tiles)
  __shared__ unsigned short As[2][256 * 64];
  __shared__ unsigned short Bs[2][256 * 64];
  mg3_core<TC, 0>(As, Bs, A + kt0 * 64, B + kt0 * 64, C + (long long)z * sC,
                  (TC*)nullptr, nullptr, nullptr,
                  N, nt * 64, lda, ldb, ldc, blockIdx.x, blockIdx.y);
}

// ---------------------------------------------------------------------------
// FUSED dispatch (verified R15-R19, 512 blocks): q_b(rope) + ABSORB + krope.
// ---------------------------------------------------------------------------
__global__ __launch_bounds__(512, 2)
void fused_qba(const bf16* __restrict__ q_a_bf, const bf16* __restrict__ wqb,
               bf16* __restrict__ q2,
               const bf16* __restrict__ kv_cat, const bf16* __restrict__ wabs,
               bf16* __restrict__ k2, bf16* __restrict__ kv_vT,
               const float* __restrict__ cosp, const float* __restrict__ sinp)
{
  __shared__ unsigned short As[2][256 * 64];
  __shared__ unsigned short Bs[2][256 * 64];
  const int f = blockIdx.x;
  if (f < 192) {                       // q_b + rope epilogue (grid 24x8)
    mg3_core<bf16, 2>(As, Bs, q_a_bf, wqb, q2, q2, cosp, sinp,
                      H * QKH, QL, QL, QL, CAT2, f % 24, f / 24);
  } else if (f < 448) {                // absorb (grid 32x8)
    const int ff = f - 192;
    mg3_core<bf16, 1>(As, Bs, kv_cat, wabs, k2, kv_vT, nullptr, nullptr,
                      H * (NOPE + VH), KVL, CAT, KVL, 0, ff % 32, ff / 32);
  } else {                             // krope: k2[h][s][128..191] = kv_cat[s][512..575]
    const int base = (f - 448) * 512 + threadIdx.x;   // 0..32767
#pragma unroll
    for (int it = 0; it < 16; ++it) {
      const int idx = base + it * 32768;              // 0..524287 (uint4 units)
      const int i8 = idx & 7;
      const int hh = (idx >> 3) & 31;
      const int s  = idx >> 8;
      *(uint4*)(k2 + ((long long)hh * S + s) * CAT2 + NOPE + i8 * 8) =
          *(const uint4*)(kv_cat + (long long)s * CAT + KVL + i8 * 8);
    }
  }
}

// ---------------------------------------------------------------------------
// FUSED norm dispatch (verified R16-R19, now 3-partial sums): rmsnorm +
// kvpost + w_q_b cast.
// ---------------------------------------------------------------------------
__global__ __launch_bounds__(256)
void fused_norm(const float* __restrict__ qkv_p,
                const float* __restrict__ g_q_a, bf16* __restrict__ q_a_bf,
                const float* __restrict__ g_kv_a,
                const float* __restrict__ cosp, const float* __restrict__ sinp,
                bf16* __restrict__ kv_cat,
                const float* __restrict__ w_q_b, bf16* __restrict__ wqb_b,
                long long poff)
{
  const int b = blockIdx.x;
  __shared__ float red[4];
  if (b < 2048) {
    const int row = b;
    const float* xr = qkv_p + (long long)row * NCAT;
    float v[6];
    float ss = 0.f;
#pragma unroll
    for (int k = 0; k < 6; k++) {
      const int c = threadIdx.x + (k << 8);
      const float t = xr[c] + xr[c + poff] + xr[c + 2 * poff];
      v[k] = t; ss += t * t;
    }
    ss = wave_sum(ss);
    if ((threadIdx.x & 63) == 0) red[threadIdx.x >> 6] = ss;
    __syncthreads();
    const float inv = rsqrtf((red[0] + red[1] + red[2] + red[3]) / (float)QL + EPS);
#pragma unroll
    for (int k = 0; k < 6; k++) {
      const int c = threadIdx.x + (k << 8);
      q_a_bf[(long long)row * QL + c] = __float2bfloat16(v[k] * inv * g_q_a[c]);
    }
  } else if (b < 4096) {
    const int s = b - 2048;
    const float* row = qkv_p + (long long)s * NCAT + QL;
    float v[2];
    float ss = 0.f;
#pragma unroll
    for (int k = 0; k < 2; k++) {
      const int c = threadIdx.x + (k << 8);
      const float t = row[c] + row[c + poff] + row[c + 2 * poff];
      v[k] = t; ss += t * t;
    }
    float ws_ = wave_sum(ss);
    if ((threadIdx.x & 63) == 0) red[threadIdx.x >> 6] = ws_;
    __syncthreads();
    const float inv = rsqrtf((red[0] + red[1] + red[2] + red[3]) / (float)KVL + EPS);
#pragma unroll
    for (int k = 0; k < 2; k++) {
      const int c = threadIdx.x + (k << 8);
      kv_cat[(long long)s * CAT + c] = __float2bfloat16(v[k] * inv * g_kv_a[c]);
    }
    if (threadIdx.x < 64) {
      const int r = threadIdx.x;
      const int c = KVL + r;
      const float x = row[c] + row[c + poff] + row[c + 2 * poff];
      const float xp = __shfl_xor(x, 32, 64);
      const float rot = (r < 32) ? -xp : xp;
      kv_cat[(long long)s * CAT + KVL + r] =
          __float2bfloat16(x * cosp[s * ROPE + r] + rot * sinp[s * ROPE + r]);
    }
  } else {
    cast_seg(w_q_b, wqb_b, (long long)H * QKH * QL / 4, b - 4096, 256);
  }
}

// ---------------------------------------------------------------------------
// MFMA flash attention v13 (verified R4-R19, ~82 us): key+value absorbed,
// head dim 192, cheap overflow-detect softmax, stage-before-compute +
// single __syncthreads skeleton.
// ---------------------------------------------------------------------------
__global__ __launch_bounds__(512, 2)
void attn_mfma13(const bf16* __restrict__ q2, const bf16* __restrict__ k2,
                 const bf16* __restrict__ kv_vT, bf16* __restrict__ ctx)
{
  __shared__ unsigned short kkl[2][32 * CAT2];  // 2 x 12,288 B  K tiles (swizzled)
  __shared__ unsigned short vtl[2][128 * 32];   // 2 x  8,192 B  V^T tiles (swizzled)
  __shared__ unsigned short ps[8][16][40];      // 10,240 B per-wave P transpose
  const int tid = threadIdx.x;
  const int bid = blockIdx.x;
  const int h  = bid & 31;
  const int qb = 15 - (bid >> 5);               // heavy blocks dispatched first
  const int w = tid >> 6, lane = tid & 63;
  const int l15 = lane & 15, g = lane >> 4;
  const int wq0 = qb * 128 + w * 16;
  const int rbase = g * 4;
  const float scale = 0.07216878364870322f;     // 1/sqrt(192)

  const bf16* ksrc[2];
#pragma unroll
  for (int j = 0; j < 2; j++) {
    const int f  = j * 512 + ((j == 1) ? (tid & 255) : tid);
    const int r  = f / 24;
    const int cg = ((f % 24) << 4) ^ ((r & 7) << 4);
    ksrc[j] = k2 + ((long long)h * S + r) * CAT2 + (cg >> 1);
  }
  const int vc = tid >> 2;
  const bf16* vsrc = kv_vT + (long long)h * VH * S + (long long)vc * S
                   + (((tid & 3) ^ ((vc >> 1) & 3)) * 8);

  auto stage = [&](int buf, int kbase) {
    gload16(ksrc[0] + (long long)kbase * CAT2, &kkl[buf][(w * 64) * 8]);
    if (tid < 256)
      gload16(ksrc[1] + (long long)kbase * CAT2, &kkl[buf][(512 + w * 64) * 8]);
    gload16(vsrc + kbase, &vtl[buf][(w * 64) * 8]);
  };

  s16x8 qf[6];
  const bf16* qp = q2 + ((long long)h * S + (wq0 + l15)) * CAT2 + g * 8;
#pragma unroll
  for (int ch = 0; ch < 6; ch++) qf[ch] = *(const s16x8*)(qp + ch * 32);

  s16x8 ones;
#pragma unroll
  for (int i = 0; i < 8; i++) ones[i] = (short)0x3F80;

  f32x4 acc[8];
#pragma unroll
  for (int nt = 0; nt < 8; nt++) acc[nt] = (f32x4){0.f, 0.f, 0.f, 0.f};
  f32x4 accl = (f32x4){0.f, 0.f, 0.f, 0.f};
  float mrow[4];
#pragma unroll
  for (int r = 0; r < 4; r++) mrow[r] = -3e38f;

  stage(0, 0);
  __syncthreads();

  const int ntb = 4 * qb + 4;
  int buf = 0;
  for (int t = 0; t < ntb; t++) {
    const int kbase = t * 32;
    if (t + 1 < ntb) stage(buf ^ 1, kbase + 32);   // overlap with compute(t)
    if (kbase <= wq0 + 15) {
      f32x4 st0 = (f32x4){0.f,0.f,0.f,0.f}, st1 = (f32x4){0.f,0.f,0.f,0.f};
      const unsigned short* kb0 = &kkl[buf][l15 * CAT2];
      const int rsw = (l15 & 7) << 4;
#pragma unroll
      for (int ch = 0; ch < 6; ch++) {
        const int cb = ((ch * 64 + g * 16) ^ rsw) >> 1;
        s16x8 b0 = *(const s16x8*)(kb0 + cb);
        s16x8 b1 = *(const s16x8*)(kb0 + 16 * CAT2 + cb);
        st0 = __builtin_amdgcn_mfma_f32_16x16x32_bf16(qf[ch], b0, st0, 0, 0, 0);
        st1 = __builtin_amdgcn_mfma_f32_16x16x32_bf16(qf[ch], b1, st1, 0, 0, 0);
      }
      float p0v[4], p1v[4];
      float pmax = 0.f;
#pragma unroll
      for (int r = 0; r < 4; r++) {
        const int qg = wq0 + rbase + r;
        const bool v0 = (kbase + l15) <= qg, v1 = (kbase + 16 + l15) <= qg;
        const float s0 = st0[r] * scale, s1 = st1[r] * scale;
        const float p0 = v0 ? __expf(s0 - mrow[r]) : 0.f;
        const float p1 = v1 ? __expf(s1 - mrow[r]) : 0.f;
        p0v[r] = p0; p1v[r] = p1;
        pmax = fmaxf(pmax, fmaxf(p0, p1));
      }
      if (__builtin_expect(__any(pmax > 2981.0f), 0)) {   // rare: growth > ~8
#pragma unroll
        for (int r = 0; r < 4; r++) {
          const int qg = wq0 + rbase + r;
          const bool v0 = (kbase + l15) <= qg, v1 = (kbase + 16 + l15) <= qg;
          const float s0 = st0[r] * scale, s1 = st1[r] * scale;
          float tmax = fmaxf(v0 ? s0 : -3e38f, v1 ? s1 : -3e38f);
#pragma unroll
          for (int off = 8; off; off >>= 1) tmax = fmaxf(tmax, __shfl_xor(tmax, off, 64));
          if (tmax > mrow[r] + 8.0f) {
            const float corr = __expf(mrow[r] - tmax);    // 0 on first tile
            mrow[r] = tmax;
#pragma unroll
            for (int nt = 0; nt < 8; nt++) acc[nt][r] *= corr;
            accl[r] *= corr;
            p0v[r] = v0 ? __expf(s0 - mrow[r]) : 0.f;
            p1v[r] = v1 ? __expf(s1 - mrow[r]) : 0.f;
          }
        }
      }
#pragma unroll
      for (int r = 0; r < 4; r++) {
        union { bf16 b; unsigned short u; } c0, c1;
        c0.b = __float2bfloat16(p0v[r]); c1.b = __float2bfloat16(p1v[r]);
        ps[w][rbase + r][l15]      = c0.u;
        ps[w][rbase + r][16 + l15] = c1.u;
      }
      asm volatile("" ::: "memory");   // order ps stores before reads (per-wave)
      s16x8 pa = *(const s16x8*)&ps[w][l15][g * 8];
      const unsigned short* vt = &vtl[buf][l15 * 32 + ((g * 8) ^ (((l15 >> 1) & 3) * 8))];
#pragma unroll
      for (int nt = 0; nt < 8; nt++) {
        s16x8 bv = *(const s16x8*)(vt + nt * 512);
        acc[nt] = __builtin_amdgcn_mfma_f32_16x16x32_bf16(pa, bv, acc[nt], 0, 0, 0);
      }
      accl = __builtin_amdgcn_mfma_f32_16x16x32_bf16(pa, ones, accl, 0, 0, 0);
    }
    __syncthreads();   // drains stage(t+1) loads + all waves done with buf
    buf ^= 1;
  }

#pragma unroll
  for (int r = 0; r < 4; r++) {
    const float inv = 1.f / accl[r];
    bf16* op = ctx + (long long)(wq0 + rbase + r) * (H * VH) + h * VH + l15;
#pragma unroll
    for (int nt = 0; nt < 8; nt++) op[nt * 16] = __float2bfloat16(acc[nt][r] * inv);
  }
}

// ---------------------------------------------------------------------------
extern "C" void kernel_launch(void* const* d_in, const int* in_sizes, int n_in,
                              void* d_out, int out_size, void* d_ws, size_t ws_size,
                              hipStream_t stream)
{
  const float* h2     = (const float*)d_in[0];
  const float* cosp   = (const float*)d_in[1];
  const float* sinp   = (const float*)d_in[2];
  const float* w_q_a  = (const float*)d_in[3];
  const float* g_q_a  = (const float*)d_in[4];
  const float* w_q_b  = (const float*)d_in[5];
  const float* w_kv_a = (const float*)d_in[6];
  const float* g_kv_a = (const float*)d_in[7];
  const float* w_uk_t = (const float*)d_in[8];
  const float* w_uv   = (const float*)d_in[9];
  const float* w_o    = (const float*)d_in[10];
  float* out = (float*)d_out;

  // ---- workspace layout (identical to R15-R19; qkv_p now 3 slices = 52 MB,
  //      same region, same liveness: dead before wo_b/q2 writes) ----
  char* ws = (char*)d_ws;
  bf16* wukb   = (bf16*)(ws);                          // 4,194,304  [H][NOPE][KVL]
  bf16* wuv_t  = (bf16*)(ws + 4194304);                // 4,194,304  [H][VH][KVL] (contiguous)
  bf16* kv_cat = (bf16*)(ws + 8388608);                // 2,359,296
  char* X = ws + 13107200;                             // 75,497,472
  char* Y = X + 75497472;                              // 67,108,864
  float* qkv_p = (float*)(X);                          // [3][2048][2112] f32 51,904,512
  bf16*  wo_b  = (bf16*)(X);                           // 33,554,432 (cast after fused_norm)
  bf16*  q2    = (bf16*)(X + 33554432);                // 25,165,824
  bf16*  ctx   = (bf16*)(X + 58720256);                // 16,777,216 (attn output)
  bf16*  hb     = (bf16*)(Y);                          // 16,777,216 (dead after qkv GEMM)
  bf16*  wcat_b = (bf16*)(Y + 16777216);               // 17,301,504 (dead after qkv)
  bf16*  wqb_b  = (bf16*)(Y);                          // 18,874,368 (cast in fused_norm)
  bf16*  q_a_bf = (bf16*)(Y + 18874368);               // 6,291,456
  bf16*  k2     = (bf16*)(Y + 25165824);               // 25,165,824
  bf16*  kv_vT  = (bf16*)(Y + 50331648);               // 16,777,216
  float* out_p1 = (float*)(Y);                         // 33,554,432 (after attn)

  // 0. ALL pre-GEMM casts in one dispatch
  cast_all<<<dim3(3216), dim3(256), 0, stream>>>(
      h2, hb, w_q_a, w_kv_a, wcat_b, w_uk_t, wukb, w_uv, wuv_t);

  // 1+4 merged: qkv partials = hb @ wcat_b^T, UNEVEN z=3 K-split:
  //   216 blocks = exactly one scheduling wave at 1 block/CU
  //   (z=4's 288 blocks ran as 256+32 = 2 waves, ~2x makespan)
  mgemm3_k3<float><<<dim3(9, 8, 3), 512, 0, stream>>>(
      hb, wcat_b, qkv_p, NCAT, D, D, NCAT, (long long)S * NCAT);

  // 2+5 + wqb-cast in one dispatch (3-partial sums)
  fused_norm<<<dim3(4352), dim3(256), 0, stream>>>(
      qkv_p, g_q_a, q_a_bf, g_kv_a, cosp, sinp, kv_cat, w_q_b, wqb_b,
      (long long)S * NCAT);

  // w_o cast: standalone full-machine dispatch
  cast_kernel<<<1024, 256, 0, stream>>>(w_o, wo_b, (long long)D * H * VH / 4);

  // 3+6 + 5b+7 + 7b FUSED: q_b(rope) + ABSORB + krope
  fused_qba<<<dim3(512), dim3(512), 0, stream>>>(
      q_a_bf, wqb_b, q2, kv_cat, (const bf16*)ws, k2, kv_vT, cosp, sinp);

  // 8. attention (verified v13) -> ctx bf16 [s][h*128+v]
  attn_mfma13<<<dim3(512), dim3(512), 0, stream>>>(q2, k2, kv_vT, ctx);

  // 10. out = ctx @ w_o^T -> f32, mgemm3 256² K-split z=2 (256 blocks = 1 wave)
  const long long ooff = (long long)(out_p1 - out);
  mgemm3<float><<<dim3(16, 8, 2), 512, 0, stream>>>(
      ctx, wo_b, out, out, nullptr, nullptr, S, D, D / 2, D, D, D,
      (long long)(D / 2), (long long)(D / 2), ooff);
  // 10b. combine: out += out_p1
  add_kernel<<<1024, 256, 0, stream>>>(out, out_p1, (long long)S * D / 4);

  (void)in_sizes; (void)n_in; (void)out_size; (void)ws_size;
}

// Round 21
// 359.859 us; speedup vs baseline: 1.1208x; 1.0022x over previous
//
#include <hip/hip_runtime.h>
#include <hip/hip_bf16.h>

typedef __hip_bfloat16 bf16;
typedef __attribute__((ext_vector_type(8))) short  s16x8;  // 8 bf16 = 4 VGPR (MFMA A/B frag)
typedef __attribute__((ext_vector_type(4))) float  f32x4;  // MFMA C/D frag

static constexpr int S    = 2048;
static constexpr int D    = 4096;
static constexpr int H    = 32;
static constexpr int QL   = 1536;
static constexpr int KVL  = 512;
static constexpr int NOPE = 128;
static constexpr int ROPE = 64;
static constexpr int QKH  = 192;
static constexpr int VH   = 128;
static constexpr int CAT  = 576;
static constexpr int CAT2 = 192;    // absorbed head dim: 128 nope + 64 rope
static constexpr int NCAT = 2112;   // QL + CAT (merged q_a/kv_a GEMM width)
static constexpr float EPS = 1e-6f;

__device__ __forceinline__ void stf(float* p, float v){ *p = v; }
__device__ __forceinline__ void stf(bf16* p, float v){ *p = __float2bfloat16(v); }

__device__ __forceinline__ float wave_sum(float v){
#pragma unroll
  for (int off = 32; off; off >>= 1) v += __shfl_xor(v, off, 64);
  return v;
}

__device__ __forceinline__ void gload16(const bf16* src, unsigned short* dst){
  __builtin_amdgcn_global_load_lds(
      (const __attribute__((address_space(1))) unsigned int*)src,
      (__attribute__((address_space(3))) unsigned int*)dst, 16, 0, 0);
}

// grid-strided f32->bf16 cast segment (256-thread blocks)
__device__ __forceinline__ void cast_seg(const float* __restrict__ in,
                                         bf16* __restrict__ out, long long n4,
                                         int brel, int nblk)
{
  long long i = (long long)brel * 256 + threadIdx.x;
  const long long stride = (long long)nblk * 256;
  for (; i < n4; i += stride) {
    float4 v = ((const float4*)in)[i];
    union { bf16 b[4]; uint2 u; } t;
    t.b[0] = __float2bfloat16(v.x); t.b[1] = __float2bfloat16(v.y);
    t.b[2] = __float2bfloat16(v.z); t.b[3] = __float2bfloat16(v.w);
    *(uint2*)(out + i * 4) = t.u;
  }
}

// ---------------------------------------------------------------------------
// standalone f32->bf16 cast (full-machine BW; used for w_o)
// ---------------------------------------------------------------------------
__global__ __launch_bounds__(256)
void cast_kernel(const float* __restrict__ in, bf16* __restrict__ out, long long n4)
{
  cast_seg(in, out, n4, blockIdx.x, gridDim.x);
}

// ---------------------------------------------------------------------------
// cast_all (verified R16-R20): ALL pre-GEMM casts in one dispatch.
// ---------------------------------------------------------------------------
__global__ __launch_bounds__(256)
void cast_all(const float* __restrict__ h2, bf16* __restrict__ hb,
              const float* __restrict__ w_q_a, const float* __restrict__ w_kv_a,
              bf16* __restrict__ wcat_b,
              const float* __restrict__ w_uk, bf16* __restrict__ wukb,
              const float* __restrict__ w_uv, bf16* __restrict__ wuv_t)
{
  const int b = blockIdx.x;
  if (b < 512) {
    cast_seg(h2, hb, (long long)S * D / 4, b, 512);
  } else if (b < 896) {
    cast_seg(w_q_a, wcat_b, (long long)QL * D / 4, b - 512, 384);
  } else if (b < 1040) {
    cast_seg(w_kv_a, wcat_b + (long long)QL * D, (long long)CAT * D / 4, b - 896, 144);
  } else if (b < 1168) {
    cast_seg(w_uk, wukb, (long long)H * NOPE * KVL / 4, b - 1040, 128);
  } else {
    // wuv tcast: in f32 [H][KVL][VH] -> out bf16 [H][VH][KVL], 32x32 tiles
    const int t2 = b - 1168;                 // 0..2047 = (VH/32) x (KVL/32) x H
    const int bx = t2 & 3, by = (t2 >> 2) & 15, bz = t2 >> 6;
    const float* in = w_uv + (long long)bz * KVL * VH;
    bf16* out = wuv_t + (long long)bz * KVL * VH;
    const int c0 = bx * 32, r0 = by * 32;
    __shared__ float t[32][33];
    const int tx = threadIdx.x & 31, ty = threadIdx.x >> 5;
#pragma unroll
    for (int p = 0; p < 4; p++)
      t[ty + p * 8][tx] = in[(long long)(r0 + ty + p * 8) * VH + c0 + tx];
    __syncthreads();
#pragma unroll
    for (int p = 0; p < 4; p++)
      out[(long long)(c0 + ty + p * 8) * KVL + r0 + tx] = __float2bfloat16(t[tx][ty + p * 8]);
  }
}

// ---------------------------------------------------------------------------
// f32 add: dst += src (K-split combine for the out GEMM)
// ---------------------------------------------------------------------------
__global__ __launch_bounds__(256)
void add_kernel(float* __restrict__ dst, const float* __restrict__ src, long long n4)
{
  long long i = (long long)blockIdx.x * 256 + threadIdx.x;
  const long long stride = (long long)gridDim.x * 256;
  for (; i < n4; i += stride) {
    float4 a = ((const float4*)dst)[i];
    const float4 b = ((const float4*)src)[i];
    a.x += b.x; a.y += b.y; a.z += b.z; a.w += b.w;
    ((float4*)dst)[i] = a;
  }
}

// ---------------------------------------------------------------------------
// mgemm3 CORE (verified R10-R20): 256x256 tile, BK=64, 8 waves, counted-vmcnt
// deep pipeline.  Monolithic 8-load stage burst + s_waitcnt vmcnt(8) keeps
// the NEXT tile's loads in flight ACROSS the barrier.
// EPI=0 plain / EPI=1 ABSORB / EPI=2 q2-ROPE (all verified).
// ---------------------------------------------------------------------------
template<typename TC, int EPI>
__device__ __forceinline__ void mg3_core(
    unsigned short (*As)[256 * 64], unsigned short (*Bs)[256 * 64],
    const bf16* __restrict__ A, const bf16* __restrict__ B,
    TC* __restrict__ C, TC* __restrict__ C2,
    const float* __restrict__ cosp, const float* __restrict__ sinp,
    int N, int K, int lda, int ldb, int ldc, int bx, int by)
{
  const int tid = threadIdx.x;
  const int w = tid >> 6;
  const int lane = tid & 63;
  const int l15 = lane & 15, g = lane >> 4;
  const int wr = w >> 2, wc = w & 3;
  const int m0 = by * 256, n0 = bx * 256;

  const bf16* asrc[4];
  const bf16* bsrc[4];
#pragma unroll
  for (int j = 0; j < 4; j++) {
    const int f = j * 512 + tid;
    const int row = f >> 3;                 // 0..255
    const int cg = ((f & 7) ^ (row & 7)) * 8;
    asrc[j] = A + (long long)(m0 + row) * lda + cg;
    int br = n0 + row; if (br >= N) br = N - 1;
    bsrc[j] = B + (long long)br * ldb + cg;
  }

  auto stage = [&](int b, int k0) {
#pragma unroll
    for (int j = 0; j < 4; j++) {
      gload16(asrc[j] + k0, &As[b][(j * 512 + w * 64) * 8]);
      gload16(bsrc[j] + k0, &Bs[b][(j * 512 + w * 64) * 8]);
    }
  };

  f32x4 acc[8][4];
#pragma unroll
  for (int i = 0; i < 8; i++)
#pragma unroll
    for (int j = 0; j < 4; j++) acc[i][j] = (f32x4){0.f, 0.f, 0.f, 0.f};

  const int ntk = K >> 6;
  stage(0, 0);

  for (int t = 0; t < ntk; ++t) {
    const int b = t & 1;
    asm volatile("" ::: "memory");
    __builtin_amdgcn_s_barrier();
    if (t + 1 < ntk) {
      stage(b ^ 1, (t + 1) << 6);
      asm volatile("s_waitcnt vmcnt(8)" ::: "memory");
    } else {
      asm volatile("s_waitcnt vmcnt(0)" ::: "memory");
    }
    __builtin_amdgcn_s_barrier();
    asm volatile("" ::: "memory");

    const unsigned short* Ab = &As[b][(wr * 128 + l15) * 64];
    const unsigned short* Bb = &Bs[b][(wc * 64 + l15) * 64];
    const int swz = l15 & 7;
#pragma unroll
    for (int kk = 0; kk < 2; ++kk) {
      const int co = (((kk * 4 + g) ^ swz) * 8);
      s16x8 a[8], bb[4];
#pragma unroll
      for (int mt = 0; mt < 8; mt++)
        a[mt] = *(const s16x8*)(Ab + mt * 1024 + co);
#pragma unroll
      for (int nt = 0; nt < 4; nt++)
        bb[nt] = *(const s16x8*)(Bb + nt * 1024 + co);
      __builtin_amdgcn_s_setprio(1);
#pragma unroll
      for (int mt = 0; mt < 8; mt++)
#pragma unroll
        for (int nt = 0; nt < 4; nt++)
          acc[mt][nt] = __builtin_amdgcn_mfma_f32_16x16x32_bf16(a[mt], bb[nt], acc[mt][nt], 0, 0, 0);
      __builtin_amdgcn_s_setprio(0);
    }
  }

  if constexpr (EPI == 2) {
    const int blk = bx * 4 + wc;
    const int hh = blk / 3;
    const int dbase = (blk % 3) * 64;
    const bool isrope = (dbase == 128);
#pragma unroll
    for (int mt = 0; mt < 8; mt++) {
      const int row0 = m0 + wr * 128 + mt * 16 + g * 4;
#pragma unroll
      for (int nt = 0; nt < 4; nt++) {
        if (!isrope) {
          const int d = dbase + nt * 16 + l15;
#pragma unroll
          for (int r = 0; r < 4; r++)
            stf((bf16*)C + ((long long)hh * S + row0 + r) * CAT2 + d, acc[mt][nt][r]);
        } else {
          const int rr = nt * 16 + l15;     // rope dim 0..63
#pragma unroll
          for (int r = 0; r < 4; r++) {
            const int srow = row0 + r;
            const float x   = acc[mt][nt][r];
            const float xp  = acc[mt][nt ^ 2][r];     // col +/- 32, in-register
            const float rot = (rr < 32) ? -xp : xp;
            stf((bf16*)C + ((long long)hh * S + srow) * CAT2 + NOPE + rr,
                x * cosp[srow * ROPE + rr] + rot * sinp[srow * ROPE + rr]);
          }
        }
      }
    }
  } else {
#pragma unroll
    for (int mt = 0; mt < 8; mt++)
#pragma unroll
      for (int nt = 0; nt < 4; nt++) {
        const int col = n0 + wc * 64 + nt * 16 + l15;
        const int row0 = m0 + wr * 128 + mt * 16 + g * 4;
        if constexpr (EPI == 0) {
          if (col < N) {
#pragma unroll
            for (int r = 0; r < 4; r++)
              stf(C + (long long)(row0 + r) * ldc + col, acc[mt][nt][r]);
          }
        } else {
          if (col < H * NOPE) {               // key-absorb -> k2[h][row][n]
            TC* dst = C + ((long long)(col >> 7) * S + row0) * CAT2 + (col & 127);
#pragma unroll
            for (int r = 0; r < 4; r++)
              stf(dst + (long long)r * CAT2, acc[mt][nt][r]);
          } else {                             // value-absorb -> kv_vT[c'][row]
            TC* dst = C2 + (long long)(col - H * NOPE) * S + row0;
#pragma unroll
            for (int r = 0; r < 4; r++)
              stf(dst + r, acc[mt][nt][r]);
          }
        }
      }
  }
}

// ---------------------------------------------------------------------------
// standalone mgemm3 (out GEMM): z-batch/K-split plumbing + core
// ---------------------------------------------------------------------------
template<typename TC, int EPI = 0>
__global__ __launch_bounds__(512, 2)
void mgemm3(const bf16* __restrict__ A, const bf16* __restrict__ B, TC* __restrict__ C,
            TC* __restrict__ C2, const float* __restrict__ cosp,
            const float* __restrict__ sinp,
            int M, int N, int K, int lda, int ldb, int ldc,
            long long sA, long long sB, long long sC)
{
  A += (long long)blockIdx.z * sA;
  B += (long long)blockIdx.z * sB;
  C += (long long)blockIdx.z * sC;
  __shared__ unsigned short As[2][256 * 64];   // 2 x 32 KB
  __shared__ unsigned short Bs[2][256 * 64];   // 2 x 32 KB
  mg3_core<TC, EPI>(As, Bs, A, B, C, C2, cosp, sinp,
                    N, K, lda, ldb, ldc, blockIdx.x, blockIdx.y);
  (void)M;
}

// ---------------------------------------------------------------------------
// mgemm3_k3 (qkv GEMM, verified R20): UNEVEN 3-way K-split, one scheduling
// wave.  216 blocks = exactly one wave at 1 block/CU; K = 64 tiles split
// 22+21+21 (kt0 0/22/43).  Consumers sum 3 partials (z-stride sC).
// ---------------------------------------------------------------------------
template<typename TC>
__global__ __launch_bounds__(512, 2)
void mgemm3_k3(const bf16* __restrict__ A, const bf16* __restrict__ B,
               TC* __restrict__ C,
               int N, int lda, int ldb, int ldc, long long sC)
{
  const int z = blockIdx.z;
  const int kt0 = z * 21 + (z > 0 ? 1 : 0);    // 0, 22, 43
  const int nt  = 21 + (z == 0 ? 1 : 0);       // 22, 21, 21  (sum = 64 tiles)
  __shared__ unsigned short As[2][256 * 64];
  __shared__ unsigned short Bs[2][256 * 64];
  mg3_core<TC, 0>(As, Bs, A + kt0 * 64, B + kt0 * 64, C + (long long)z * sC,
                  (TC*)nullptr, nullptr, nullptr,
                  N, nt * 64, lda, ldb, ldc, blockIdx.x, blockIdx.y);
}

// ---------------------------------------------------------------------------
// FUSED dispatch (verified R15-R20, 512 blocks): q_b(rope) + ABSORB + krope.
// Packing bound: makespan >= 32 tile-units (proof in R21 notes) -- at bound.
// ---------------------------------------------------------------------------
__global__ __launch_bounds__(512, 2)
void fused_qba(const bf16* __restrict__ q_a_bf, const bf16* __restrict__ wqb,
               bf16* __restrict__ q2,
               const bf16* __restrict__ kv_cat, const bf16* __restrict__ wabs,
               bf16* __restrict__ k2, bf16* __restrict__ kv_vT,
               const float* __restrict__ cosp, const float* __restrict__ sinp)
{
  __shared__ unsigned short As[2][256 * 64];
  __shared__ unsigned short Bs[2][256 * 64];
  const int f = blockIdx.x;
  if (f < 192) {                       // q_b + rope epilogue (grid 24x8)
    mg3_core<bf16, 2>(As, Bs, q_a_bf, wqb, q2, q2, cosp, sinp,
                      H * QKH, QL, QL, QL, CAT2, f % 24, f / 24);
  } else if (f < 448) {                // absorb (grid 32x8)
    const int ff = f - 192;
    mg3_core<bf16, 1>(As, Bs, kv_cat, wabs, k2, kv_vT, nullptr, nullptr,
                      H * (NOPE + VH), KVL, CAT, KVL, 0, ff % 32, ff / 32);
  } else {                             // krope: k2[h][s][128..191] = kv_cat[s][512..575]
    const int base = (f - 448) * 512 + threadIdx.x;   // 0..32767
#pragma unroll
    for (int it = 0; it < 16; ++it) {
      const int idx = base + it * 32768;              // 0..524287 (uint4 units)
      const int i8 = idx & 7;
      const int hh = (idx >> 3) & 31;
      const int s  = idx >> 8;
      *(uint4*)(k2 + ((long long)hh * S + s) * CAT2 + NOPE + i8 * 8) =
          *(const uint4*)(kv_cat + (long long)s * CAT + KVL + i8 * 8);
    }
  }
}

// ---------------------------------------------------------------------------
// FUSED norm dispatch (verified R16-R20, 3-partial sums): rmsnorm + kvpost +
// w_q_b cast.
// ---------------------------------------------------------------------------
__global__ __launch_bounds__(256)
void fused_norm(const float* __restrict__ qkv_p,
                const float* __restrict__ g_q_a, bf16* __restrict__ q_a_bf,
                const float* __restrict__ g_kv_a,
                const float* __restrict__ cosp, const float* __restrict__ sinp,
                bf16* __restrict__ kv_cat,
                const float* __restrict__ w_q_b, bf16* __restrict__ wqb_b,
                long long poff)
{
  const int b = blockIdx.x;
  __shared__ float red[4];
  if (b < 2048) {
    const int row = b;
    const float* xr = qkv_p + (long long)row * NCAT;
    float v[6];
    float ss = 0.f;
#pragma unroll
    for (int k = 0; k < 6; k++) {
      const int c = threadIdx.x + (k << 8);
      const float t = xr[c] + xr[c + poff] + xr[c + 2 * poff];
      v[k] = t; ss += t * t;
    }
    ss = wave_sum(ss);
    if ((threadIdx.x & 63) == 0) red[threadIdx.x >> 6] = ss;
    __syncthreads();
    const float inv = rsqrtf((red[0] + red[1] + red[2] + red[3]) / (float)QL + EPS);
#pragma unroll
    for (int k = 0; k < 6; k++) {
      const int c = threadIdx.x + (k << 8);
      q_a_bf[(long long)row * QL + c] = __float2bfloat16(v[k] * inv * g_q_a[c]);
    }
  } else if (b < 4096) {
    const int s = b - 2048;
    const float* row = qkv_p + (long long)s * NCAT + QL;
    float v[2];
    float ss = 0.f;
#pragma unroll
    for (int k = 0; k < 2; k++) {
      const int c = threadIdx.x + (k << 8);
      const float t = row[c] + row[c + poff] + row[c + 2 * poff];
      v[k] = t; ss += t * t;
    }
    float ws_ = wave_sum(ss);
    if ((threadIdx.x & 63) == 0) red[threadIdx.x >> 6] = ws_;
    __syncthreads();
    const float inv = rsqrtf((red[0] + red[1] + red[2] + red[3]) / (float)KVL + EPS);
#pragma unroll
    for (int k = 0; k < 2; k++) {
      const int c = threadIdx.x + (k << 8);
      kv_cat[(long long)s * CAT + c] = __float2bfloat16(v[k] * inv * g_kv_a[c]);
    }
    if (threadIdx.x < 64) {
      const int r = threadIdx.x;
      const int c = KVL + r;
      const float x = row[c] + row[c + poff] + row[c + 2 * poff];
      const float xp = __shfl_xor(x, 32, 64);
      const float rot = (r < 32) ? -xp : xp;
      kv_cat[(long long)s * CAT + KVL + r] =
          __float2bfloat16(x * cosp[s * ROPE + r] + rot * sinp[s * ROPE + r]);
    }
  } else {
    cast_seg(w_q_b, wqb_b, (long long)H * QKH * QL / 4, b - 4096, 256);
  }
}

// ---------------------------------------------------------------------------
// MFMA flash attention v13 (verified R4-R20, ~82 us): key+value absorbed,
// head dim 192, cheap overflow-detect softmax, stage-before-compute +
// single __syncthreads skeleton.
// ---------------------------------------------------------------------------
__global__ __launch_bounds__(512, 2)
void attn_mfma13(const bf16* __restrict__ q2, const bf16* __restrict__ k2,
                 const bf16* __restrict__ kv_vT, bf16* __restrict__ ctx)
{
  __shared__ unsigned short kkl[2][32 * CAT2];  // 2 x 12,288 B  K tiles (swizzled)
  __shared__ unsigned short vtl[2][128 * 32];   // 2 x  8,192 B  V^T tiles (swizzled)
  __shared__ unsigned short ps[8][16][40];      // 10,240 B per-wave P transpose
  const int tid = threadIdx.x;
  const int bid = blockIdx.x;
  const int h  = bid & 31;
  const int qb = 15 - (bid >> 5);               // heavy blocks dispatched first
  const int w = tid >> 6, lane = tid & 63;
  const int l15 = lane & 15, g = lane >> 4;
  const int wq0 = qb * 128 + w * 16;
  const int rbase = g * 4;
  const float scale = 0.07216878364870322f;     // 1/sqrt(192)

  const bf16* ksrc[2];
#pragma unroll
  for (int j = 0; j < 2; j++) {
    const int f  = j * 512 + ((j == 1) ? (tid & 255) : tid);
    const int r  = f / 24;
    const int cg = ((f % 24) << 4) ^ ((r & 7) << 4);
    ksrc[j] = k2 + ((long long)h * S + r) * CAT2 + (cg >> 1);
  }
  const int vc = tid >> 2;
  const bf16* vsrc = kv_vT + (long long)h * VH * S + (long long)vc * S
                   + (((tid & 3) ^ ((vc >> 1) & 3)) * 8);

  auto stage = [&](int buf, int kbase) {
    gload16(ksrc[0] + (long long)kbase * CAT2, &kkl[buf][(w * 64) * 8]);
    if (tid < 256)
      gload16(ksrc[1] + (long long)kbase * CAT2, &kkl[buf][(512 + w * 64) * 8]);
    gload16(vsrc + kbase, &vtl[buf][(w * 64) * 8]);
  };

  s16x8 qf[6];
  const bf16* qp = q2 + ((long long)h * S + (wq0 + l15)) * CAT2 + g * 8;
#pragma unroll
  for (int ch = 0; ch < 6; ch++) qf[ch] = *(const s16x8*)(qp + ch * 32);

  s16x8 ones;
#pragma unroll
  for (int i = 0; i < 8; i++) ones[i] = (short)0x3F80;

  f32x4 acc[8];
#pragma unroll
  for (int nt = 0; nt < 8; nt++) acc[nt] = (f32x4){0.f, 0.f, 0.f, 0.f};
  f32x4 accl = (f32x4){0.f, 0.f, 0.f, 0.f};
  float mrow[4];
#pragma unroll
  for (int r = 0; r < 4; r++) mrow[r] = -3e38f;

  stage(0, 0);
  __syncthreads();

  const int ntb = 4 * qb + 4;
  int buf = 0;
  for (int t = 0; t < ntb; t++) {
    const int kbase = t * 32;
    if (t + 1 < ntb) stage(buf ^ 1, kbase + 32);   // overlap with compute(t)
    if (kbase <= wq0 + 15) {
      f32x4 st0 = (f32x4){0.f,0.f,0.f,0.f}, st1 = (f32x4){0.f,0.f,0.f,0.f};
      const unsigned short* kb0 = &kkl[buf][l15 * CAT2];
      const int rsw = (l15 & 7) << 4;
#pragma unroll
      for (int ch = 0; ch < 6; ch++) {
        const int cb = ((ch * 64 + g * 16) ^ rsw) >> 1;
        s16x8 b0 = *(const s16x8*)(kb0 + cb);
        s16x8 b1 = *(const s16x8*)(kb0 + 16 * CAT2 + cb);
        st0 = __builtin_amdgcn_mfma_f32_16x16x32_bf16(qf[ch], b0, st0, 0, 0, 0);
        st1 = __builtin_amdgcn_mfma_f32_16x16x32_bf16(qf[ch], b1, st1, 0, 0, 0);
      }
      float p0v[4], p1v[4];
      float pmax = 0.f;
#pragma unroll
      for (int r = 0; r < 4; r++) {
        const int qg = wq0 + rbase + r;
        const bool v0 = (kbase + l15) <= qg, v1 = (kbase + 16 + l15) <= qg;
        const float s0 = st0[r] * scale, s1 = st1[r] * scale;
        const float p0 = v0 ? __expf(s0 - mrow[r]) : 0.f;
        const float p1 = v1 ? __expf(s1 - mrow[r]) : 0.f;
        p0v[r] = p0; p1v[r] = p1;
        pmax = fmaxf(pmax, fmaxf(p0, p1));
      }
      if (__builtin_expect(__any(pmax > 2981.0f), 0)) {   // rare: growth > ~8
#pragma unroll
        for (int r = 0; r < 4; r++) {
          const int qg = wq0 + rbase + r;
          const bool v0 = (kbase + l15) <= qg, v1 = (kbase + 16 + l15) <= qg;
          const float s0 = st0[r] * scale, s1 = st1[r] * scale;
          float tmax = fmaxf(v0 ? s0 : -3e38f, v1 ? s1 : -3e38f);
#pragma unroll
          for (int off = 8; off; off >>= 1) tmax = fmaxf(tmax, __shfl_xor(tmax, off, 64));
          if (tmax > mrow[r] + 8.0f) {
            const float corr = __expf(mrow[r] - tmax);    // 0 on first tile
            mrow[r] = tmax;
#pragma unroll
            for (int nt = 0; nt < 8; nt++) acc[nt][r] *= corr;
            accl[r] *= corr;
            p0v[r] = v0 ? __expf(s0 - mrow[r]) : 0.f;
            p1v[r] = v1 ? __expf(s1 - mrow[r]) : 0.f;
          }
        }
      }
#pragma unroll
      for (int r = 0; r < 4; r++) {
        union { bf16 b; unsigned short u; } c0, c1;
        c0.b = __float2bfloat16(p0v[r]); c1.b = __float2bfloat16(p1v[r]);
        ps[w][rbase + r][l15]      = c0.u;
        ps[w][rbase + r][16 + l15] = c1.u;
      }
      asm volatile("" ::: "memory");   // order ps stores before reads (per-wave)
      s16x8 pa = *(const s16x8*)&ps[w][l15][g * 8];
      const unsigned short* vt = &vtl[buf][l15 * 32 + ((g * 8) ^ (((l15 >> 1) & 3) * 8))];
#pragma unroll
      for (int nt = 0; nt < 8; nt++) {
        s16x8 bv = *(const s16x8*)(vt + nt * 512);
        acc[nt] = __builtin_amdgcn_mfma_f32_16x16x32_bf16(pa, bv, acc[nt], 0, 0, 0);
      }
      accl = __builtin_amdgcn_mfma_f32_16x16x32_bf16(pa, ones, accl, 0, 0, 0);
    }
    __syncthreads();   // drains stage(t+1) loads + all waves done with buf
    buf ^= 1;
  }

#pragma unroll
  for (int r = 0; r < 4; r++) {
    const float inv = 1.f / accl[r];
    bf16* op = ctx + (long long)(wq0 + rbase + r) * (H * VH) + h * VH + l15;
#pragma unroll
    for (int nt = 0; nt < 8; nt++) op[nt * 16] = __float2bfloat16(acc[nt][r] * inv);
  }
}

// ---------------------------------------------------------------------------
extern "C" void kernel_launch(void* const* d_in, const int* in_sizes, int n_in,
                              void* d_out, int out_size, void* d_ws, size_t ws_size,
                              hipStream_t stream)
{
  const float* h2     = (const float*)d_in[0];
  const float* cosp   = (const float*)d_in[1];
  const float* sinp   = (const float*)d_in[2];
  const float* w_q_a  = (const float*)d_in[3];
  const float* g_q_a  = (const float*)d_in[4];
  const float* w_q_b  = (const float*)d_in[5];
  const float* w_kv_a = (const float*)d_in[6];
  const float* g_kv_a = (const float*)d_in[7];
  const float* w_uk_t = (const float*)d_in[8];
  const float* w_uv   = (const float*)d_in[9];
  const float* w_o    = (const float*)d_in[10];
  float* out = (float*)d_out;

  // ---- workspace layout (verified R15-R20) ----
  char* ws = (char*)d_ws;
  bf16* wukb   = (bf16*)(ws);                          // 4,194,304  [H][NOPE][KVL]
  bf16* wuv_t  = (bf16*)(ws + 4194304);                // 4,194,304  [H][VH][KVL] (contiguous)
  bf16* kv_cat = (bf16*)(ws + 8388608);                // 2,359,296
  char* X = ws + 13107200;                             // 75,497,472
  char* Y = X + 75497472;                              // 67,108,864
  float* qkv_p = (float*)(X);                          // [3][2048][2112] f32 51,904,512
  bf16*  wo_b  = (bf16*)(X);                           // 33,554,432 (cast after fused_norm)
  bf16*  q2    = (bf16*)(X + 33554432);                // 25,165,824
  bf16*  ctx   = (bf16*)(X + 58720256);                // 16,777,216 (attn output)
  bf16*  hb     = (bf16*)(Y);                          // 16,777,216 (dead after qkv GEMM)
  bf16*  wcat_b = (bf16*)(Y + 16777216);               // 17,301,504 (dead after qkv)
  bf16*  wqb_b  = (bf16*)(Y);                          // 18,874,368 (cast in fused_norm)
  bf16*  q_a_bf = (bf16*)(Y + 18874368);               // 6,291,456
  bf16*  k2     = (bf16*)(Y + 25165824);               // 25,165,824
  bf16*  kv_vT  = (bf16*)(Y + 50331648);               // 16,777,216
  float* out_p1 = (float*)(Y);                         // 33,554,432 (after attn)

  // 0. ALL pre-GEMM casts in one dispatch
  cast_all<<<dim3(3216), dim3(256), 0, stream>>>(
      h2, hb, w_q_a, w_kv_a, wcat_b, w_uk_t, wukb, w_uv, wuv_t);

  // 1+4 merged: qkv partials = hb @ wcat_b^T, UNEVEN z=3 K-split (one wave)
  mgemm3_k3<float><<<dim3(9, 8, 3), 512, 0, stream>>>(
      hb, wcat_b, qkv_p, NCAT, D, D, NCAT, (long long)S * NCAT);

  // 2+5 + wqb-cast in one dispatch (3-partial sums)
  fused_norm<<<dim3(4352), dim3(256), 0, stream>>>(
      qkv_p, g_q_a, q_a_bf, g_kv_a, cosp, sinp, kv_cat, w_q_b, wqb_b,
      (long long)S * NCAT);

  // w_o cast: standalone full-machine dispatch
  cast_kernel<<<1024, 256, 0, stream>>>(w_o, wo_b, (long long)D * H * VH / 4);

  // 3+6 + 5b+7 + 7b FUSED: q_b(rope) + ABSORB + krope
  fused_qba<<<dim3(512), dim3(512), 0, stream>>>(
      q_a_bf, wqb_b, q2, kv_cat, (const bf16*)ws, k2, kv_vT, cosp, sinp);

  // 8. attention (verified v13) -> ctx bf16 [s][h*128+v]
  attn_mfma13<<<dim3(512), dim3(512), 0, stream>>>(q2, k2, kv_vT, ctx);

  // 10. out = ctx @ w_o^T -> f32, mgemm3 256² K-split z=2 (256 blocks = 1 wave)
  const long long ooff = (long long)(out_p1 - out);
  mgemm3<float><<<dim3(16, 8, 2), 512, 0, stream>>>(
      ctx, wo_b, out, out, nullptr, nullptr, S, D, D / 2, D, D, D,
      (long long)(D / 2), (long long)(D / 2), ooff);
  // 10b. combine: out += out_p1
  add_kernel<<<1024, 256, 0, stream>>>(out, out_p1, (long long)S * D / 4);

  (void)in_sizes; (void)n_in; (void)out_size; (void)ws_size;
}